// Round 8
// baseline (2901.583 us; speedup 1.0000x reference)
//
#include <hip/hip_runtime.h>
#include <hip/hip_bf16.h>

#define DIMSZ 1024
#define SEQLEN 4096
#define NHEAD 16
#define NX 16777216L     // x elements
#define NW 1048576L      // weight elements each
#define KVSPLITS 8

typedef __attribute__((ext_vector_type(8))) short bf16x8;
typedef __attribute__((ext_vector_type(4))) float f32x4;

__device__ __forceinline__ unsigned short f2bf(float f) {
    union { float f; unsigned int i; } c; c.f = f;
    unsigned int x = c.i;
    unsigned int r = (x + 0x7fffu + ((x >> 16) & 1u)) >> 16;
    return (unsigned short)r;
}

// pack two f32 -> two bf16 (round-half-up) in one perm
__device__ __forceinline__ unsigned int pk2(float lo, float hi) {
    union { float f; unsigned int i; } a, b; a.f = lo; b.f = hi;
    return __builtin_amdgcn_perm(b.i + 0x8000u, a.i + 0x8000u, 0x07060302u);
}

// register-resident bf16x8 -> 8 floats
__device__ __forceinline__ void unp8r(bf16x8 v, float* f) {
    union { bf16x8 s; uint4 w; } u; u.s = v;
    union { unsigned int i; float f; } c;
    c.i = u.w.x << 16;           f[0] = c.f;
    c.i = u.w.x & 0xffff0000u;   f[1] = c.f;
    c.i = u.w.y << 16;           f[2] = c.f;
    c.i = u.w.y & 0xffff0000u;   f[3] = c.f;
    c.i = u.w.z << 16;           f[4] = c.f;
    c.i = u.w.z & 0xffff0000u;   f[5] = c.f;
    c.i = u.w.w << 16;           f[6] = c.f;
    c.i = u.w.w & 0xffff0000u;   f[7] = c.f;
}

__device__ __forceinline__ void async16(const void* g, void* l) {
    __builtin_amdgcn_global_load_lds(
        (const __attribute__((address_space(1))) void*)g,
        (__attribute__((address_space(3))) void*)l,
        16, 0, 0);
}

// ---------------- kernel 1: casts + weight packing + stdp passthrough ------
__global__ __launch_bounds__(256) void cast_pack(
    const float* __restrict__ x, const float* __restrict__ Wq,
    const float* __restrict__ Wk, const float* __restrict__ Wv,
    const float* __restrict__ Wo, const float* __restrict__ stdp,
    unsigned short* __restrict__ xb, unsigned short* __restrict__ Wqkv,
    unsigned short* __restrict__ Wob, float* __restrict__ outTail)
{
    long i4 = ((long)blockIdx.x * 256 + threadIdx.x) * 4;
    const float* src; unsigned short* dst; long off;
    if (i4 < NX)               { src = x;  dst = xb;          off = i4; }
    else if (i4 < NX + NW)     { src = Wq; dst = Wqkv;        off = i4 - NX; }
    else if (i4 < NX + 2*NW)   { src = Wk; dst = Wqkv + NW;   off = i4 - NX - NW; }
    else if (i4 < NX + 3*NW)   { src = Wv; dst = Wqkv + 2*NW; off = i4 - NX - 2*NW; }
    else                       { src = Wo; dst = Wob;         off = i4 - NX - 3*NW; }
    float4 v = *(const float4*)(src + off);
    union { unsigned short u[4]; uint2 p; } o;
    o.u[0] = f2bf(v.x); o.u[1] = f2bf(v.y); o.u[2] = f2bf(v.z); o.u[3] = f2bf(v.w);
    *(uint2*)(dst + off) = o.p;
    if (blockIdx.x == 0 && threadIdx.x < NHEAD) outTail[threadIdx.x] = stdp[threadIdx.x];
}

// ---------------- kernel 2: fused QKV GEMM — hybrid operand feed -----------
// 256x256 tile, 16 waves (4Mx4N, 64x64/wave), BK=64.
// B (weights) double-buffered in LDS (64 KB total -> 2 blocks/CU, 32 waves);
// A fragments read DIRECTLY from global (L1-served: 4 waves/wm-group share
// lines within a phase; working set 16 KB/kt << 32 KB L1), register
// double-buffered aA/aB one kt ahead.
// vm stream per kt: [a(kt+1) x8, B-stage(kt+2) x2]. Gates: top vmcnt(2)
// (a(kt) landed; B(kt+1) may fly), end vmcnt(10)+barrier (B(kt+1) visible).
// Prologue [B0x2, a0x8, B1x2] + vmcnt(10). Tails: kt14 end vmcnt(8),
// kt15 top vmcnt(0). lgkm gates (2/0 per half) overlap ds_reads with MFMA.
__global__ __launch_bounds__(1024, 8) void qkv_gemm8(
    const unsigned short* __restrict__ A, const unsigned short* __restrict__ W,
    const float* __restrict__ bq, const float* __restrict__ bk,
    const float* __restrict__ bv,
    unsigned short* __restrict__ Qb, unsigned short* __restrict__ Kb,
    unsigned short* __restrict__ Vb)
{
    __shared__ __align__(16) char SM[65536];   // 2 bufs x B(32K); epilogue reuse
    const int t = threadIdx.x;
    const int wave = t >> 6, lane = t & 63;
    const int lr = lane & 15, lq = lane >> 4;
    const int wm = wave >> 2, wn = wave & 3;
    const int m0 = blockIdx.x * 256;
    const int c0 = blockIdx.y * 256;

    // B staging: LDS dest linear (global_load_lds), source chunk pre-swizzled.
    const int sc = (((t & 7) ^ ((t >> 3) & 7)) * 8);
    const unsigned short* pB = W + (long)(c0 + (t >> 3)) * DIMSZ + sc;

    // A fragments from global: row m0+wm*64+16i+lr, k = kt*64 + s*32 + lq*8
    const unsigned short* pAW = A + (long)(m0 + wm * 64 + lr) * DIMSZ + lq * 8;

    // ds_read swizzle: frag (row, kchunk) at chunk (kchunk ^ (lr&7))
    const int xo = ((lq ^ (lr & 7)) << 4);
    const char* BB = SM + (wn * 64 + lr) * 128;

    f32x4 acc[4][4];
    #pragma unroll
    for (int i = 0; i < 4; ++i)
        #pragma unroll
        for (int j = 0; j < 4; ++j) acc[i][j] = (f32x4){0.f, 0.f, 0.f, 0.f};

    bf16x8 aA[4][2], aB[4][2];

    // B-stage piece H (col-half) of tile Q: 16 KB per inst (1024 thr x 16 B)
#define STAGEB(Q, H) do {                                                       \
        if ((Q) < 16) {                                                         \
            const unsigned short* s_ = pB + (long)(H) * 131072 + (Q) * 64;      \
            char* d_ = SM + (((Q) & 1) << 15) + (H) * 16384 + wave * 1024;      \
            async16(s_, d_);                                                    \
        }                                                                       \
    } while (0)

#define MFMA8(B0_, J0_, B1_, J1_, AC, S)                                          \
    acc[0][J0_] = __builtin_amdgcn_mfma_f32_16x16x32_bf16(B0_, AC[0][S], acc[0][J0_], 0, 0, 0); \
    acc[1][J0_] = __builtin_amdgcn_mfma_f32_16x16x32_bf16(B0_, AC[1][S], acc[1][J0_], 0, 0, 0); \
    acc[2][J0_] = __builtin_amdgcn_mfma_f32_16x16x32_bf16(B0_, AC[2][S], acc[2][J0_], 0, 0, 0); \
    acc[3][J0_] = __builtin_amdgcn_mfma_f32_16x16x32_bf16(B0_, AC[3][S], acc[3][J0_], 0, 0, 0); \
    acc[0][J1_] = __builtin_amdgcn_mfma_f32_16x16x32_bf16(B1_, AC[0][S], acc[0][J1_], 0, 0, 0); \
    acc[1][J1_] = __builtin_amdgcn_mfma_f32_16x16x32_bf16(B1_, AC[1][S], acc[1][J1_], 0, 0, 0); \
    acc[2][J1_] = __builtin_amdgcn_mfma_f32_16x16x32_bf16(B1_, AC[2][S], acc[2][J1_], 0, 0, 0); \
    acc[3][J1_] = __builtin_amdgcn_mfma_f32_16x16x32_bf16(B1_, AC[3][S], acc[3][J1_], 0, 0, 0);

#define KTCORE(KT_, AC, AN, TOPW, ALOAD) do {                                   \
        const int bo = ((KT_) & 1) << 15;                                       \
        asm volatile("s_waitcnt vmcnt(" #TOPW ")" ::: "memory");                \
        __builtin_amdgcn_sched_barrier(0);                                      \
        bf16x8 b0, b1, b2, b3;                                                  \
        b0 = *(const bf16x8*)(BB + bo + 0 * 2048 + xo);                         \
        b1 = *(const bf16x8*)(BB + bo + 1 * 2048 + xo);                         \
        __builtin_amdgcn_sched_barrier(0);                                      \
        b2 = *(const bf16x8*)(BB + bo + 2 * 2048 + xo);                         \
        b3 = *(const bf16x8*)(BB + bo + 3 * 2048 + xo);                         \
        __builtin_amdgcn_sched_barrier(0);                                      \
        if (ALOAD) {                                                            \
            AN[0][0] = *(const bf16x8*)(pAW + 0 * 16384 + ((KT_) + 1) * 64);    \
            AN[0][1] = *(const bf16x8*)(pAW + 0 * 16384 + ((KT_) + 1) * 64 + 32);\
            AN[1][0] = *(const bf16x8*)(pAW + 1 * 16384 + ((KT_) + 1) * 64);    \
            AN[1][1] = *(const bf16x8*)(pAW + 1 * 16384 + ((KT_) + 1) * 64 + 32);\
            AN[2][0] = *(const bf16x8*)(pAW + 2 * 16384 + ((KT_) + 1) * 64);    \
            AN[2][1] = *(const bf16x8*)(pAW + 2 * 16384 + ((KT_) + 1) * 64 + 32);\
            AN[3][0] = *(const bf16x8*)(pAW + 3 * 16384 + ((KT_) + 1) * 64);    \
            AN[3][1] = *(const bf16x8*)(pAW + 3 * 16384 + ((KT_) + 1) * 64 + 32);\
        }                                                                       \
        asm volatile("s_waitcnt lgkmcnt(2)" ::: "memory");                      \
        __builtin_amdgcn_sched_barrier(0);                                      \
        __builtin_amdgcn_s_setprio(1);                                          \
        MFMA8(b0, 0, b1, 1, AC, 0)                                              \
        __builtin_amdgcn_s_setprio(0);                                          \
        asm volatile("s_waitcnt lgkmcnt(0)" ::: "memory");                      \
        __builtin_amdgcn_sched_barrier(0);                                      \
        __builtin_amdgcn_s_setprio(1);                                          \
        MFMA8(b2, 2, b3, 3, AC, 0)                                              \
        __builtin_amdgcn_s_setprio(0);                                          \
        b0 = *(const bf16x8*)(BB + bo + 0 * 2048 + (xo ^ 64));                  \
        b1 = *(const bf16x8*)(BB + bo + 1 * 2048 + (xo ^ 64));                  \
        __builtin_amdgcn_sched_barrier(0);                                      \
        b2 = *(const bf16x8*)(BB + bo + 2 * 2048 + (xo ^ 64));                  \
        b3 = *(const bf16x8*)(BB + bo + 3 * 2048 + (xo ^ 64));                  \
        __builtin_amdgcn_sched_barrier(0);                                      \
        asm volatile("s_waitcnt lgkmcnt(2)" ::: "memory");                      \
        __builtin_amdgcn_sched_barrier(0);                                      \
        __builtin_amdgcn_s_setprio(1);                                          \
        MFMA8(b0, 0, b1, 1, AC, 1)                                              \
        __builtin_amdgcn_s_setprio(0);                                          \
        asm volatile("s_waitcnt lgkmcnt(0)" ::: "memory");                      \
        __builtin_amdgcn_sched_barrier(0);                                      \
        __builtin_amdgcn_s_barrier();                                           \
        STAGEB((KT_) + 2, 0); STAGEB((KT_) + 2, 1);                             \
        __builtin_amdgcn_s_setprio(1);                                          \
        MFMA8(b2, 2, b3, 3, AC, 1)                                              \
        __builtin_amdgcn_s_setprio(0);                                          \
    } while (0)

    // prologue: order [B0 x2, a0 x8, B1 x2] -> vmcnt(10) drains B0
    STAGEB(0, 0); STAGEB(0, 1);
    __builtin_amdgcn_sched_barrier(0);
    aA[0][0] = *(const bf16x8*)(pAW + 0 * 16384);
    aA[0][1] = *(const bf16x8*)(pAW + 0 * 16384 + 32);
    aA[1][0] = *(const bf16x8*)(pAW + 1 * 16384);
    aA[1][1] = *(const bf16x8*)(pAW + 1 * 16384 + 32);
    aA[2][0] = *(const bf16x8*)(pAW + 2 * 16384);
    aA[2][1] = *(const bf16x8*)(pAW + 2 * 16384 + 32);
    aA[3][0] = *(const bf16x8*)(pAW + 3 * 16384);
    aA[3][1] = *(const bf16x8*)(pAW + 3 * 16384 + 32);
    __builtin_amdgcn_sched_barrier(0);
    STAGEB(1, 0); STAGEB(1, 1);
    __builtin_amdgcn_sched_barrier(0);
    asm volatile("s_waitcnt vmcnt(10)" ::: "memory");
    __builtin_amdgcn_s_barrier();

    for (int ktp = 0; ktp < 7; ++ktp) {
        const int k0 = ktp * 2;
        KTCORE(k0, aA, aB, 2, 1);
        asm volatile("s_waitcnt vmcnt(10)" ::: "memory");
        __builtin_amdgcn_s_barrier();
        KTCORE(k0 + 1, aB, aA, 2, 1);
        asm volatile("s_waitcnt vmcnt(10)" ::: "memory");
        __builtin_amdgcn_s_barrier();
    }
    KTCORE(14, aA, aB, 2, 1);
    asm volatile("s_waitcnt vmcnt(8)" ::: "memory");
    __builtin_amdgcn_s_barrier();
    KTCORE(15, aB, aA, 0, 0);
#undef KTCORE
#undef MFMA8
#undef STAGEB

    // ---- epilogue: 2 passes of 128 rows (Cs = 64 KB) ----
    const int proj = c0 >> 10;                         // block-uniform
    const float* bias = proj == 0 ? bq : (proj == 1 ? bk : bv);
    const bool qk = proj < 2;
    const int cb = (c0 & 1023) + wn * 64;
    const int q4 = lq * 4;
    unsigned short* dstp = proj == 0 ? Qb : (proj == 1 ? Kb : Vb);
    const int colsh = (t & 31) * 8;                    // tile-local col (shorts)
    const int h = ((c0 >> 6) + (colsh >> 6)) & 15;
    const int b_ = m0 >> 12;
    unsigned short* dbase = dstp + ((long)(b_ * 16 + h) * SEQLEN) * 64 + (colsh & 63);

    #pragma unroll
    for (int p = 0; p < 2; ++p) {
        __syncthreads();
        if ((wm >> 1) == p) {
            #pragma unroll
            for (int j = 0; j < 4; ++j) {
                const float4 b4 = *(const float4*)(bias + cb + 16 * j + q4);
                #pragma unroll
                for (int i = 0; i < 4; ++i) {
                    float v0 = acc[i][j][0] + b4.x, v1 = acc[i][j][1] + b4.y;
                    float v2 = acc[i][j][2] + b4.z, v3 = acc[i][j][3] + b4.w;
                    if (qk) {
                        v0 = v0 > 0.f ? v0 + 1.f : __expf(v0);
                        v1 = v1 > 0.f ? v1 + 1.f : __expf(v1);
                        v2 = v2 > 0.f ? v2 + 1.f : __expf(v2);
                        v3 = v3 > 0.f ? v3 + 1.f : __expf(v3);
                    }
                    const int lrow = (wm & 1) * 64 + 16 * i + lr;
                    int byte = lrow * 512 + wn * 128 + j * 32 + q4 * 2;
                    byte ^= (lrow & 7) << 4;
                    uint2 pkd; pkd.x = pk2(v0, v1); pkd.y = pk2(v2, v3);
                    *(uint2*)(SM + byte) = pkd;
                }
            }
        }
        __syncthreads();
        #pragma unroll
        for (int u = 0; u < 4; ++u) {
            const int flat = u * 16384 + t * 16;
            const int lrow = flat >> 9;
            uint4 val = *(const uint4*)(SM + (flat ^ ((lrow & 7) << 4)));
            const int n = (m0 + p * 128 + lrow) & 4095;
            *(uint4*)(dbase + (long)n * 64) = val;
        }
    }
}

// ---------------- kernel 3: KV partials + Ksum partials via MFMA ----------
__global__ __launch_bounds__(256) void kv_reduce(
    const unsigned short* __restrict__ Kb, const unsigned short* __restrict__ Vb,
    float* __restrict__ KVp, float* __restrict__ Ksump)
{
    __shared__ __align__(16) char LDS[65536];   // 2 iters x (Kt 16K + Vt 16K)
    int bh = blockIdx.x, split = blockIdx.y, t = threadIdx.x;
    int wave = t >> 6, lane = t & 63, lr = lane & 15, lq = lane >> 4;

    const int nl = t & 127;            // local n row this thread stages
    const int dh = (t >> 7) * 32;      // d-half (wave-uniform)
    const int vrow = 16 * wave + lr;

    f32x4 acc[4];
    #pragma unroll
    for (int j = 0; j < 4; ++j) acc[j] = (f32x4){0.f, 0.f, 0.f, 0.f};
    float ksp[4] = {0.f, 0.f, 0.f, 0.f};

    for (int half = 0; half < 2; ++half) {
        const unsigned short* Kbase = Kb + ((long)bh * SEQLEN + split * 512 + half * 256) * 64;
        const unsigned short* Vbase = Vb + ((long)bh * SEQLEN + split * 512 + half * 256) * 64;

        union Q2S { uint4 q[4]; unsigned short s[32]; };
        Q2S kq[2], vq[2];
        #pragma unroll
        for (int it = 0; it < 2; ++it) {
            const unsigned short* kp = Kbase + (long)(it * 128 + nl) * 64 + dh;
            const unsigned short* vp = Vbase + (long)(it * 128 + nl) * 64 + dh;
            #pragma unroll
            for (int g = 0; g < 4; ++g) {
                kq[it].q[g] = *(const uint4*)(kp + g * 8);
                vq[it].q[g] = *(const uint4*)(vp + g * 8);
            }
        }
        if (half) __syncthreads();   // prior pass's reads complete before overwrite
        // transposed swizzled stores: elem (n=nl, d=dh+e) at d*256 + (2n ^ ((d&7)<<4))
        #pragma unroll
        for (int it = 0; it < 2; ++it) {
            char* buf = LDS + it * 32768;
            #pragma unroll
            for (int e = 0; e < 32; ++e) {
                const int d = dh + e;
                const int a = d * 256 + ((nl * 2) ^ ((d & 7) << 4));
                *(unsigned short*)(buf + a) = kq[it].s[e];
                *(unsigned short*)(buf + 16384 + a) = vq[it].s[e];
            }
        }
        __syncthreads();

        #pragma unroll
        for (int it = 0; it < 2; ++it) {
            const char* buf = LDS + it * 32768;
            #pragma unroll
            for (int ns = 0; ns < 4; ++ns) {
                const int xoff = (ns * 64 + lq * 16) ^ ((lr & 7) << 4);
                bf16x8 af = *(const bf16x8*)(buf + 16384 + vrow * 256 + xoff);
                bf16x8 bfr[4];
                #pragma unroll
                for (int j = 0; j < 4; ++j)
                    bfr[j] = *(const bf16x8*)(buf + (16 * j + lr) * 256 + xoff);
                if (wave == 0) {
                    #pragma unroll
                    for (int j = 0; j < 4; ++j) {
                        float kf[8]; unp8r(bfr[j], kf);
                        ksp[j] += ((kf[0] + kf[1]) + (kf[2] + kf[3]))
                                + ((kf[4] + kf[5]) + (kf[6] + kf[7]));
                    }
                }
                #pragma unroll
                for (int j = 0; j < 4; ++j)
                    acc[j] = __builtin_amdgcn_mfma_f32_16x16x32_bf16(bfr[j], af, acc[j], 0, 0, 0);
            }
        }
    }

    float* kp = KVp + ((long)split * 64 + bh) * 4096;
    const int q4 = lq * 4;
    #pragma unroll
    for (int j = 0; j < 4; ++j)
        *(f32x4*)(kp + vrow * 64 + 16 * j + q4) = acc[j];

    if (wave == 0) {
        #pragma unroll
        for (int j = 0; j < 4; ++j) {
            float s = ksp[j];
            s += __shfl_xor(s, 16);
            s += __shfl_xor(s, 32);
            if (lane < 16)
                Ksump[((long)split * 64 + bh) * 64 + 16 * j + lr] = s;
        }
    }
}

// ---------------- kernel 3b: fold partials -> KV bf16 + Ksum f32 ----------
__global__ __launch_bounds__(256) void kv_final(
    const float* __restrict__ KVp, const float* __restrict__ Ksump,
    unsigned short* __restrict__ KVb, float* __restrict__ Ksum)
{
    int bh = blockIdx.x, t = threadIdx.x;
    float s[16];
    #pragma unroll
    for (int g = 0; g < 16; ++g) s[g] = 0.f;
    for (int sp = 0; sp < KVSPLITS; ++sp) {
        const float* src = KVp + ((long)sp * 64 + bh) * 4096 + t * 16;
        #pragma unroll
        for (int g = 0; g < 4; ++g) {
            float4 v = *(const float4*)(src + g * 4);
            s[g * 4 + 0] += v.x; s[g * 4 + 1] += v.y;
            s[g * 4 + 2] += v.z; s[g * 4 + 3] += v.w;
        }
    }
    uint4 o0, o1;
    o0.x = pk2(s[0], s[1]);  o0.y = pk2(s[2], s[3]);
    o0.z = pk2(s[4], s[5]);  o0.w = pk2(s[6], s[7]);
    o1.x = pk2(s[8], s[9]);  o1.y = pk2(s[10], s[11]);
    o1.z = pk2(s[12], s[13]); o1.w = pk2(s[14], s[15]);
    *(uint4*)(KVb + (long)bh * 4096 + t * 16) = o0;
    *(uint4*)(KVb + (long)bh * 4096 + t * 16 + 8) = o1;
    if (t < 16) {
        float4 a = {0.f, 0.f, 0.f, 0.f};
        for (int p = 0; p < KVSPLITS; p += 4) {
            #pragma unroll
            for (int q = 0; q < 4; ++q) {
                float4 v = *(const float4*)(Ksump + ((long)(p + q) * 64 + bh) * 64 + t * 4);
                a.x += v.x; a.y += v.y; a.z += v.z; a.w += v.w;
            }
        }
        *(float4*)(Ksum + bh * 64 + t * 4) = a;
    }
}

// ---------------- kernel 4: numerator MFMA + fused denominator -> attn bf16
__global__ __launch_bounds__(256) void attn_kernel(
    const unsigned short* __restrict__ Qb, const unsigned short* __restrict__ KVb,
    const float* __restrict__ Ksum, const float* __restrict__ stdp,
    unsigned short* __restrict__ attn)
{
    __shared__ unsigned short Cs[256 * 72];   // output staging
    int t = threadIdx.x;
    int bh = blockIdx.y;   // 64
    int b = bh >> 4, h = bh & 15;

    int wave = t >> 6, lane = t & 63, lr = lane & 15, lk = (lane >> 4) * 8;
    const unsigned short* kvb = KVb + (long)bh * 4096;
    const float* ksb = Ksum + bh * 64;

    // hoist KV fragments + Ksum slices (block-invariant)
    bf16x8 bfrh[2][4];
    float ksf[2][8];
    #pragma unroll
    for (int s = 0; s < 2; ++s) {
        #pragma unroll
        for (int j = 0; j < 4; ++j)
            bfrh[s][j] = *(const bf16x8*)(kvb + (16 * j + lr) * 64 + s * 32 + lk);
        float4 ka = *(const float4*)(ksb + s * 32 + lk);
        float4 kb2 = *(const float4*)(ksb + s * 32 + lk + 4);
        ksf[s][0] = ka.x; ksf[s][1] = ka.y; ksf[s][2] = ka.z; ksf[s][3] = ka.w;
        ksf[s][4] = kb2.x; ksf[s][5] = kb2.y; ksf[s][6] = kb2.z; ksf[s][7] = kb2.w;
    }
    float sg = 1.f / (1.f + __expf(-stdp[h]));
    int q4 = (lane >> 4) * 4;

    for (int c = 0; c < 2; ++c) {
        int rc = blockIdx.x * 2 + c;
        int rowbase = rc * 256 + wave * 64;

        f32x4 acc[4][4];
        #pragma unroll
        for (int i = 0; i < 4; ++i)
            #pragma unroll
            for (int j = 0; j < 4; ++j) acc[i][j] = (f32x4){0.f, 0.f, 0.f, 0.f};
        float ds[4] = {0.f, 0.f, 0.f, 0.f};

        #pragma unroll
        for (int s = 0; s < 2; ++s) {
            bf16x8 af[4];
            #pragma unroll
            for (int i = 0; i < 4; ++i)
                af[i] = *(const bf16x8*)(Qb + ((long)bh * SEQLEN + rowbase + 16 * i + lr) * 64 + s * 32 + lk);
            #pragma unroll
            for (int i = 0; i < 4; ++i) {
                float qf[8]; unp8r(af[i], qf);
                #pragma unroll
                for (int e = 0; e < 8; ++e) ds[i] += qf[e] * ksf[s][e];
            }
            #pragma unroll
            for (int i = 0; i < 4; ++i)
                #pragma unroll
                for (int j = 0; j < 4; ++j)
                    acc[i][j] = __builtin_amdgcn_mfma_f32_16x16x32_bf16(bfrh[s][j], af[i], acc[i][j], 0, 0, 0);
        }

        float dinv_i[4];
        #pragma unroll
        for (int i = 0; i < 4; ++i) {
            float d = ds[i];
            d += __shfl_xor(d, 16);
            d += __shfl_xor(d, 32);
            dinv_i[i] = sg / (d + 1e-6f);
        }

        #pragma unroll
        for (int j = 0; j < 4; ++j) {
            int v0c = 16 * j + q4;
            #pragma unroll
            for (int i = 0; i < 4; ++i) {
                int row = wave * 64 + 16 * i + lr;
                float d = dinv_i[i];
                uint2 pkd;
                pkd.x = pk2(acc[i][j][0] * d, acc[i][j][1] * d);
                pkd.y = pk2(acc[i][j][2] * d, acc[i][j][3] * d);
                *(uint2*)(Cs + row * 72 + v0c) = pkd;
            }
        }
        __syncthreads();
        #pragma unroll
        for (int u = 0; u < 8; ++u) {
            int row = u * 32 + (t >> 3);
            int nn = rc * 256 + row;
            long a = ((long)(b * SEQLEN + nn)) * DIMSZ + h * 64 + (t & 7) * 8;
            *(uint4*)(attn + a) = *(const uint4*)(Cs + row * 72 + (t & 7) * 8);
        }
        __syncthreads();   // Cs reuse across chunks
    }
}

// ---------------- kernel 5: output GEMM — 256x256 tile, 16 waves ----------
__global__ __launch_bounds__(1024, 1) void out_gemm8(
    const unsigned short* __restrict__ A, const unsigned short* __restrict__ W,
    const float* __restrict__ bo, float* __restrict__ out)
{
    __shared__ __align__(16) char SM[131072];
    const int t = threadIdx.x;
    const int wave = t >> 6, lane = t & 63;
    const int lr = lane & 15, lq = lane >> 4;
    const int wm = wave >> 2, wn = wave & 3;
    const int m0 = blockIdx.x * 256;
    const int c0 = blockIdx.y * 256;

    const int sc = (((t & 7) ^ ((t >> 3) & 7)) * 8);
    const unsigned short* pA = A + (long)(m0 + (t >> 3)) * DIMSZ + sc;
    const unsigned short* pB = W + (long)(c0 + (t >> 3)) * DIMSZ + sc;
    char* ldsW = SM + wave * 1024;

    const int xo = ((lq ^ (lr & 7)) << 4);
    const char* ABase = SM + wm * 8192 + lr * 128;
    const char* BBase = SM + 32768 + (wn * 64 + lr) * 128;

    f32x4 acc[4][4];
    #pragma unroll
    for (int i = 0; i < 4; ++i)
        #pragma unroll
        for (int j = 0; j < 4; ++j) acc[i][j] = (f32x4){0.f, 0.f, 0.f, 0.f};

#define STAGE(Q, O) do {                                                        \
        if ((Q) < 16) {                                                         \
            const int isB_ = ((O) < 2) ? 1 : 0;                                 \
            const int half_ = isB_ ? (O) : ((O) - 2);                           \
            const unsigned short* s_ = (isB_ ? pB : pA)                         \
                                       + (long)half_ * 131072 + (Q) * 64;       \
            char* d_ = ldsW + (((Q) & 1) << 16) + isB_ * 32768 + half_ * 16384; \
            async16(s_, d_);                                                    \
        }                                                                       \
    } while (0)

    STAGE(0, 0); STAGE(0, 1); STAGE(0, 2); STAGE(0, 3);
    STAGE(1, 0); STAGE(1, 1); STAGE(1, 2);
    asm volatile("s_waitcnt vmcnt(3)" ::: "memory");
    __builtin_amdgcn_s_barrier();

    for (int kt = 0; kt < 16; ++kt) {
        const int buf = (kt & 1) << 16;
        bf16x8 a[4], b[4];

        // K-half 0
        b[0] = *(const bf16x8*)(BBase + buf + 0 * 2048 + xo);
        b[1] = *(const bf16x8*)(BBase + buf + 1 * 2048 + xo);
        #pragma unroll
        for (int i = 0; i < 4; ++i)
            a[i] = *(const bf16x8*)(ABase + buf + i * 2048 + xo);
        __builtin_amdgcn_sched_barrier(0);
        b[2] = *(const bf16x8*)(BBase + buf + 2 * 2048 + xo);
        b[3] = *(const bf16x8*)(BBase + buf + 3 * 2048 + xo);
        __builtin_amdgcn_sched_barrier(0);
        STAGE(kt + 1, 3);

        asm volatile("s_waitcnt lgkmcnt(2)" ::: "memory");
        __builtin_amdgcn_sched_barrier(0);
        __builtin_amdgcn_s_setprio(1);
        #pragma unroll
        for (int i = 0; i < 4; ++i)
            #pragma unroll
            for (int j = 0; j < 2; ++j)
                acc[i][j] = __builtin_amdgcn_mfma_f32_16x16x32_bf16(
                    b[j], a[i], acc[i][j], 0, 0, 0);
        __builtin_amdgcn_s_setprio(0);

        asm volatile("s_waitcnt lgkmcnt(0)" ::: "memory");
        __builtin_amdgcn_sched_barrier(0);
        __builtin_amdgcn_s_setprio(1);
        #pragma unroll
        for (int i = 0; i < 4; ++i)
            #pragma unroll
            for (int j = 2; j < 4; ++j)
                acc[i][j] = __builtin_amdgcn_mfma_f32_16x16x32_bf16(
                    b[j], a[i], acc[i][j], 0, 0, 0);
        __builtin_amdgcn_s_setprio(0);

        // K-half 1
        b[0] = *(const bf16x8*)(BBase + buf + 0 * 2048 + (xo ^ 64));
        b[1] = *(const bf16x8*)(BBase + buf + 1 * 2048 + (xo ^ 64));
        #pragma unroll
        for (int i = 0; i < 4; ++i)
            a[i] = *(const bf16x8*)(ABase + buf + i * 2048 + (xo ^ 64));
        __builtin_amdgcn_sched_barrier(0);
        b[2] = *(const bf16x8*)(BBase + buf + 2 * 2048 + (xo ^ 64));
        b[3] = *(const bf16x8*)(BBase + buf + 3 * 2048 + (xo ^ 64));
        __builtin_amdgcn_sched_barrier(0);

        asm volatile("s_waitcnt lgkmcnt(2)" ::: "memory");
        __builtin_amdgcn_sched_barrier(0);
        __builtin_amdgcn_s_setprio(1);
        #pragma unroll
        for (int i = 0; i < 4; ++i)
            #pragma unroll
            for (int j = 0; j < 2; ++j)
                acc[i][j] = __builtin_amdgcn_mfma_f32_16x16x32_bf16(
                    b[j], a[i], acc[i][j], 0, 0, 0);
        __builtin_amdgcn_s_setprio(0);

        asm volatile("s_waitcnt lgkmcnt(0)" ::: "memory");
        __builtin_amdgcn_sched_barrier(0);
        __builtin_amdgcn_s_barrier();
        STAGE(kt + 2, 0); STAGE(kt + 2, 1); STAGE(kt + 2, 2);

        __builtin_amdgcn_s_setprio(1);
        #pragma unroll
        for (int i = 0; i < 4; ++i)
            #pragma unroll
            for (int j = 2; j < 4; ++j)
                acc[i][j] = __builtin_amdgcn_mfma_f32_16x16x32_bf16(
                    b[j], a[i], acc[i][j], 0, 0, 0);
        __builtin_amdgcn_s_setprio(0);

        if (kt < 14)       asm volatile("s_waitcnt vmcnt(3)" ::: "memory");
        else if (kt == 14) asm volatile("s_waitcnt vmcnt(0)" ::: "memory");
        __builtin_amdgcn_s_barrier();
    }
#undef STAGE

    const int q4 = lq * 4;
    #pragma unroll
    for (int j = 0; j < 4; ++j) {
        const int c = c0 + wn * 64 + 16 * j + q4;
        const float4 b4 = *(const float4*)(bo + c);
        #pragma unroll
        for (int i = 0; i < 4; ++i) {
            const int gm = m0 + wm * 64 + 16 * i + lr;
            float4 v;
            v.x = acc[i][j][0] + b4.x; v.y = acc[i][j][1] + b4.y;
            v.z = acc[i][j][2] + b4.z; v.w = acc[i][j][3] + b4.w;
            *(float4*)(out + (long)gm * DIMSZ + c) = v;
        }
    }
}

extern "C" void kernel_launch(void* const* d_in, const int* in_sizes, int n_in,
                              void* d_out, int out_size, void* d_ws, size_t ws_size,
                              hipStream_t stream) {
    const float* x    = (const float*)d_in[0];
    const float* Wq   = (const float*)d_in[1];
    const float* bq   = (const float*)d_in[2];
    const float* Wk   = (const float*)d_in[3];
    const float* bk   = (const float*)d_in[4];
    const float* Wv   = (const float*)d_in[5];
    const float* bv   = (const float*)d_in[6];
    const float* Wo   = (const float*)d_in[7];
    const float* bo   = (const float*)d_in[8];
    const float* stdp = (const float*)d_in[9];
    float* out = (float*)d_out;

    char* ws = (char*)d_ws;
    unsigned short* xb   = (unsigned short*)(ws);
    float*          KVp  = (float*)(ws);                          // 8.4 MB
    unsigned short* attn = (unsigned short*)(ws);                 // 32 MB
    unsigned short* Wqkv = (unsigned short*)(ws + 33554432L);     // 6 MB
    float*          Ksump= (float*)(ws + 33554432L);              // 128 KB
    unsigned short* KVb  = (unsigned short*)(ws + 33816576L);     // 512 KB
    float*          Ksum = (float*)(ws + 34340864L);              // 16 KB
    unsigned short* Wob  = (unsigned short*)(ws + 39845888L);     // 2 MB
    unsigned short* Qb   = (unsigned short*)(ws + 41943040L);     // 32 MB
    unsigned short* Kb   = (unsigned short*)(ws + 75497472L);     // 32 MB
    unsigned short* Vb   = (unsigned short*)(ws + 109051904L);    // 32 MB

    cast_pack<<<20480, 256, 0, stream>>>(x, Wq, Wk, Wv, Wo, stdp, xb, Wqkv, Wob,
                                         out + 16777216L);
    qkv_gemm8<<<dim3(64, 12), 1024, 0, stream>>>(xb, Wqkv, bq, bk, bv, Qb, Kb, Vb);
    kv_reduce<<<dim3(64, KVSPLITS), 256, 0, stream>>>(Kb, Vb, KVp, Ksump);
    kv_final<<<64, 256, 0, stream>>>(KVp, Ksump, KVb, Ksum);
    attn_kernel<<<dim3(8, 64), 256, 0, stream>>>(Qb, KVb, Ksum, stdp, attn);
    out_gemm8<<<dim3(64, 4), 1024, 0, stream>>>(attn, Wob, bo, out);
}

// Round 9
// 446.588 us; speedup vs baseline: 6.4972x; 6.4972x over previous
//
#include <hip/hip_runtime.h>
#include <hip/hip_bf16.h>

#define DIMSZ 1024
#define SEQLEN 4096
#define NHEAD 16
#define NX 16777216L     // x elements
#define NW 1048576L      // weight elements each
#define KVSPLITS 8

typedef __attribute__((ext_vector_type(8))) short bf16x8;
typedef __attribute__((ext_vector_type(4))) float f32x4;

__device__ __forceinline__ unsigned short f2bf(float f) {
    union { float f; unsigned int i; } c; c.f = f;
    unsigned int x = c.i;
    unsigned int r = (x + 0x7fffu + ((x >> 16) & 1u)) >> 16;
    return (unsigned short)r;
}

// pack two f32 -> two bf16 (round-half-up) in one perm
__device__ __forceinline__ unsigned int pk2(float lo, float hi) {
    union { float f; unsigned int i; } a, b; a.f = lo; b.f = hi;
    return __builtin_amdgcn_perm(b.i + 0x8000u, a.i + 0x8000u, 0x07060302u);
}

// register-resident bf16x8 -> 8 floats
__device__ __forceinline__ void unp8r(bf16x8 v, float* f) {
    union { bf16x8 s; uint4 w; } u; u.s = v;
    union { unsigned int i; float f; } c;
    c.i = u.w.x << 16;           f[0] = c.f;
    c.i = u.w.x & 0xffff0000u;   f[1] = c.f;
    c.i = u.w.y << 16;           f[2] = c.f;
    c.i = u.w.y & 0xffff0000u;   f[3] = c.f;
    c.i = u.w.z << 16;           f[4] = c.f;
    c.i = u.w.z & 0xffff0000u;   f[5] = c.f;
    c.i = u.w.w << 16;           f[6] = c.f;
    c.i = u.w.w & 0xffff0000u;   f[7] = c.f;
}

__device__ __forceinline__ void async16(const void* g, void* l) {
    __builtin_amdgcn_global_load_lds(
        (const __attribute__((address_space(1))) void*)g,
        (__attribute__((address_space(3))) void*)l,
        16, 0, 0);
}

// ---------------- kernel 1: casts + weight packing + stdp passthrough ------
__global__ __launch_bounds__(256) void cast_pack(
    const float* __restrict__ x, const float* __restrict__ Wq,
    const float* __restrict__ Wk, const float* __restrict__ Wv,
    const float* __restrict__ Wo, const float* __restrict__ stdp,
    unsigned short* __restrict__ xb, unsigned short* __restrict__ Wqkv,
    unsigned short* __restrict__ Wob, float* __restrict__ outTail)
{
    long i4 = ((long)blockIdx.x * 256 + threadIdx.x) * 4;
    const float* src; unsigned short* dst; long off;
    if (i4 < NX)               { src = x;  dst = xb;          off = i4; }
    else if (i4 < NX + NW)     { src = Wq; dst = Wqkv;        off = i4 - NX; }
    else if (i4 < NX + 2*NW)   { src = Wk; dst = Wqkv + NW;   off = i4 - NX - NW; }
    else if (i4 < NX + 3*NW)   { src = Wv; dst = Wqkv + 2*NW; off = i4 - NX - 2*NW; }
    else                       { src = Wo; dst = Wob;         off = i4 - NX - 3*NW; }
    float4 v = *(const float4*)(src + off);
    union { unsigned short u[4]; uint2 p; } o;
    o.u[0] = f2bf(v.x); o.u[1] = f2bf(v.y); o.u[2] = f2bf(v.z); o.u[3] = f2bf(v.w);
    *(uint2*)(dst + off) = o.p;
    if (blockIdx.x == 0 && threadIdx.x < NHEAD) outTail[threadIdx.x] = stdp[threadIdx.x];
}

// ---------------- kernel 2: fused QKV GEMM — hybrid operand feed -----------
// 256x256 tile, 16 waves (4Mx4N, 64x64/wave), BK=64, 1 block/CU.
// B (weights) double-buffered in LDS (64 KB); A fragments read DIRECTLY from
// global into a SINGLE transient reg buffer a[4][2] at the top of each kt
// (L1-served: the 4 waves of a wm-group read identical lines; 32 KB/kt
// unique per block). VGPR budget: acc 64 + a 32 + b 16 + addr ~12 <= 128
// (launch_bounds(1024,4) caps at 128 — R8's (1024,8) capped at 64 and
// spilled everything; that was the 2.7 ms regression).
// Per kt: top vmcnt(0) (A landed; stale stages drained), lgkm gates 2/0 per
// half overlap ds_reads with MFMA, mid barrier -> STAGEB(kt+2), end barrier.
__global__ __launch_bounds__(1024, 4) void qkv_gemm8(
    const unsigned short* __restrict__ A, const unsigned short* __restrict__ W,
    const float* __restrict__ bq, const float* __restrict__ bk,
    const float* __restrict__ bv,
    unsigned short* __restrict__ Qb, unsigned short* __restrict__ Kb,
    unsigned short* __restrict__ Vb)
{
    __shared__ __align__(16) char SM[65536];   // 2 bufs x B(32K); epilogue reuse
    const int t = threadIdx.x;
    const int wave = t >> 6, lane = t & 63;
    const int lr = lane & 15, lq = lane >> 4;
    const int wm = wave >> 2, wn = wave & 3;
    const int m0 = blockIdx.x * 256;
    const int c0 = blockIdx.y * 256;

    // B staging: LDS dest linear (global_load_lds), source chunk pre-swizzled.
    const int sc = (((t & 7) ^ ((t >> 3) & 7)) * 8);
    const unsigned short* pB = W + (long)(c0 + (t >> 3)) * DIMSZ + sc;

    // A fragments from global: row m0+wm*64+16i+lr, k = kt*64 + s*32 + lq*8
    const unsigned short* pAW = A + (long)(m0 + wm * 64 + lr) * DIMSZ + lq * 8;

    // ds_read swizzle: frag (row, kchunk) at chunk (kchunk ^ (lr&7))
    const int xo = ((lq ^ (lr & 7)) << 4);
    const char* BB = SM + (wn * 64 + lr) * 128;

    f32x4 acc[4][4];
    #pragma unroll
    for (int i = 0; i < 4; ++i)
        #pragma unroll
        for (int j = 0; j < 4; ++j) acc[i][j] = (f32x4){0.f, 0.f, 0.f, 0.f};

    // B-stage piece H (col-half) of tile Q: 16 KB per inst (1024 thr x 16 B)
#define STAGEB(Q, H) do {                                                       \
        if ((Q) < 16) {                                                         \
            const unsigned short* s_ = pB + (long)(H) * 131072 + (Q) * 64;      \
            char* d_ = SM + (((Q) & 1) << 15) + (H) * 16384 + wave * 1024;      \
            async16(s_, d_);                                                    \
        }                                                                       \
    } while (0)

    // prologue: stage B of kt0 and kt1, drain, barrier
    STAGEB(0, 0); STAGEB(0, 1);
    STAGEB(1, 0); STAGEB(1, 1);
    asm volatile("s_waitcnt vmcnt(0)" ::: "memory");
    __builtin_amdgcn_s_barrier();

    for (int kt = 0; kt < 16; ++kt) {
        const int bo = (kt & 1) << 15;
        bf16x8 a[4][2];
        bf16x8 b0, b1, b2, b3;

        // ---- A fragments for this kt (global, L1-served) ----
        #pragma unroll
        for (int i = 0; i < 4; ++i) {
            a[i][0] = *(const bf16x8*)(pAW + i * 16384 + kt * 64);
            a[i][1] = *(const bf16x8*)(pAW + i * 16384 + kt * 64 + 32);
        }
        __builtin_amdgcn_sched_barrier(0);

        // ---- K-half 0: B reads + gated MFMA ----
        b0 = *(const bf16x8*)(BB + bo + 0 * 2048 + xo);
        b1 = *(const bf16x8*)(BB + bo + 1 * 2048 + xo);
        __builtin_amdgcn_sched_barrier(0);
        b2 = *(const bf16x8*)(BB + bo + 2 * 2048 + xo);
        b3 = *(const bf16x8*)(BB + bo + 3 * 2048 + xo);
        __builtin_amdgcn_sched_barrier(0);

        asm volatile("s_waitcnt vmcnt(0)" ::: "memory");    // A landed (+ old stages)
        asm volatile("s_waitcnt lgkmcnt(2)" ::: "memory");  // b0,b1 ready
        __builtin_amdgcn_sched_barrier(0);
        __builtin_amdgcn_s_setprio(1);
        #pragma unroll
        for (int i = 0; i < 4; ++i) {
            acc[i][0] = __builtin_amdgcn_mfma_f32_16x16x32_bf16(b0, a[i][0], acc[i][0], 0, 0, 0);
            acc[i][1] = __builtin_amdgcn_mfma_f32_16x16x32_bf16(b1, a[i][0], acc[i][1], 0, 0, 0);
        }
        __builtin_amdgcn_s_setprio(0);

        asm volatile("s_waitcnt lgkmcnt(0)" ::: "memory");
        __builtin_amdgcn_sched_barrier(0);
        __builtin_amdgcn_s_setprio(1);
        #pragma unroll
        for (int i = 0; i < 4; ++i) {
            acc[i][2] = __builtin_amdgcn_mfma_f32_16x16x32_bf16(b2, a[i][0], acc[i][2], 0, 0, 0);
            acc[i][3] = __builtin_amdgcn_mfma_f32_16x16x32_bf16(b3, a[i][0], acc[i][3], 0, 0, 0);
        }
        __builtin_amdgcn_s_setprio(0);

        // ---- K-half 1 ----
        b0 = *(const bf16x8*)(BB + bo + 0 * 2048 + (xo ^ 64));
        b1 = *(const bf16x8*)(BB + bo + 1 * 2048 + (xo ^ 64));
        __builtin_amdgcn_sched_barrier(0);
        b2 = *(const bf16x8*)(BB + bo + 2 * 2048 + (xo ^ 64));
        b3 = *(const bf16x8*)(BB + bo + 3 * 2048 + (xo ^ 64));
        __builtin_amdgcn_sched_barrier(0);

        asm volatile("s_waitcnt lgkmcnt(2)" ::: "memory");
        __builtin_amdgcn_sched_barrier(0);
        __builtin_amdgcn_s_setprio(1);
        #pragma unroll
        for (int i = 0; i < 4; ++i) {
            acc[i][0] = __builtin_amdgcn_mfma_f32_16x16x32_bf16(b0, a[i][1], acc[i][0], 0, 0, 0);
            acc[i][1] = __builtin_amdgcn_mfma_f32_16x16x32_bf16(b1, a[i][1], acc[i][1], 0, 0, 0);
        }
        __builtin_amdgcn_s_setprio(0);

        asm volatile("s_waitcnt lgkmcnt(0)" ::: "memory");  // all B reads of buf done
        __builtin_amdgcn_sched_barrier(0);
        __builtin_amdgcn_s_barrier();            // all waves done reading this buf
        STAGEB(kt + 2, 0); STAGEB(kt + 2, 1);    // overwrite with kt+2's B

        __builtin_amdgcn_s_setprio(1);
        #pragma unroll
        for (int i = 0; i < 4; ++i) {
            acc[i][2] = __builtin_amdgcn_mfma_f32_16x16x32_bf16(b2, a[i][1], acc[i][2], 0, 0, 0);
            acc[i][3] = __builtin_amdgcn_mfma_f32_16x16x32_bf16(b3, a[i][1], acc[i][3], 0, 0, 0);
        }
        __builtin_amdgcn_s_setprio(0);
        __builtin_amdgcn_s_barrier();
    }
#undef STAGEB

    // ---- epilogue: 2 passes of 128 rows (Cs = 64 KB) ----
    const int proj = c0 >> 10;                         // block-uniform
    const float* bias = proj == 0 ? bq : (proj == 1 ? bk : bv);
    const bool qk = proj < 2;
    const int cb = (c0 & 1023) + wn * 64;
    const int q4 = lq * 4;
    unsigned short* dstp = proj == 0 ? Qb : (proj == 1 ? Kb : Vb);
    const int colsh = (t & 31) * 8;                    // tile-local col (shorts)
    const int h = ((c0 >> 6) + (colsh >> 6)) & 15;
    const int b_ = m0 >> 12;
    unsigned short* dbase = dstp + ((long)(b_ * 16 + h) * SEQLEN) * 64 + (colsh & 63);

    #pragma unroll
    for (int p = 0; p < 2; ++p) {
        __syncthreads();
        if ((wm >> 1) == p) {
            #pragma unroll
            for (int j = 0; j < 4; ++j) {
                const float4 b4 = *(const float4*)(bias + cb + 16 * j + q4);
                #pragma unroll
                for (int i = 0; i < 4; ++i) {
                    float v0 = acc[i][j][0] + b4.x, v1 = acc[i][j][1] + b4.y;
                    float v2 = acc[i][j][2] + b4.z, v3 = acc[i][j][3] + b4.w;
                    if (qk) {
                        v0 = v0 > 0.f ? v0 + 1.f : __expf(v0);
                        v1 = v1 > 0.f ? v1 + 1.f : __expf(v1);
                        v2 = v2 > 0.f ? v2 + 1.f : __expf(v2);
                        v3 = v3 > 0.f ? v3 + 1.f : __expf(v3);
                    }
                    const int lrow = (wm & 1) * 64 + 16 * i + lr;
                    int byte = lrow * 512 + wn * 128 + j * 32 + q4 * 2;
                    byte ^= (lrow & 7) << 4;
                    uint2 pkd; pkd.x = pk2(v0, v1); pkd.y = pk2(v2, v3);
                    *(uint2*)(SM + byte) = pkd;
                }
            }
        }
        __syncthreads();
        #pragma unroll
        for (int u = 0; u < 4; ++u) {
            const int flat = u * 16384 + t * 16;
            const int lrow = flat >> 9;
            uint4 val = *(const uint4*)(SM + (flat ^ ((lrow & 7) << 4)));
            const int n = (m0 + p * 128 + lrow) & 4095;
            *(uint4*)(dbase + (long)n * 64) = val;
        }
    }
}

// ---------------- kernel 3: KV partials + Ksum partials via MFMA ----------
__global__ __launch_bounds__(256) void kv_reduce(
    const unsigned short* __restrict__ Kb, const unsigned short* __restrict__ Vb,
    float* __restrict__ KVp, float* __restrict__ Ksump)
{
    __shared__ __align__(16) char LDS[65536];   // 2 iters x (Kt 16K + Vt 16K)
    int bh = blockIdx.x, split = blockIdx.y, t = threadIdx.x;
    int wave = t >> 6, lane = t & 63, lr = lane & 15, lq = lane >> 4;

    const int nl = t & 127;            // local n row this thread stages
    const int dh = (t >> 7) * 32;      // d-half (wave-uniform)
    const int vrow = 16 * wave + lr;

    f32x4 acc[4];
    #pragma unroll
    for (int j = 0; j < 4; ++j) acc[j] = (f32x4){0.f, 0.f, 0.f, 0.f};
    float ksp[4] = {0.f, 0.f, 0.f, 0.f};

    for (int half = 0; half < 2; ++half) {
        const unsigned short* Kbase = Kb + ((long)bh * SEQLEN + split * 512 + half * 256) * 64;
        const unsigned short* Vbase = Vb + ((long)bh * SEQLEN + split * 512 + half * 256) * 64;

        union Q2S { uint4 q[4]; unsigned short s[32]; };
        Q2S kq[2], vq[2];
        #pragma unroll
        for (int it = 0; it < 2; ++it) {
            const unsigned short* kp = Kbase + (long)(it * 128 + nl) * 64 + dh;
            const unsigned short* vp = Vbase + (long)(it * 128 + nl) * 64 + dh;
            #pragma unroll
            for (int g = 0; g < 4; ++g) {
                kq[it].q[g] = *(const uint4*)(kp + g * 8);
                vq[it].q[g] = *(const uint4*)(vp + g * 8);
            }
        }
        if (half) __syncthreads();   // prior pass's reads complete before overwrite
        // transposed swizzled stores: elem (n=nl, d=dh+e) at d*256 + (2n ^ ((d&7)<<4))
        #pragma unroll
        for (int it = 0; it < 2; ++it) {
            char* buf = LDS + it * 32768;
            #pragma unroll
            for (int e = 0; e < 32; ++e) {
                const int d = dh + e;
                const int a = d * 256 + ((nl * 2) ^ ((d & 7) << 4));
                *(unsigned short*)(buf + a) = kq[it].s[e];
                *(unsigned short*)(buf + 16384 + a) = vq[it].s[e];
            }
        }
        __syncthreads();

        #pragma unroll
        for (int it = 0; it < 2; ++it) {
            const char* buf = LDS + it * 32768;
            #pragma unroll
            for (int ns = 0; ns < 4; ++ns) {
                const int xoff = (ns * 64 + lq * 16) ^ ((lr & 7) << 4);
                bf16x8 af = *(const bf16x8*)(buf + 16384 + vrow * 256 + xoff);
                bf16x8 bfr[4];
                #pragma unroll
                for (int j = 0; j < 4; ++j)
                    bfr[j] = *(const bf16x8*)(buf + (16 * j + lr) * 256 + xoff);
                if (wave == 0) {
                    #pragma unroll
                    for (int j = 0; j < 4; ++j) {
                        float kf[8]; unp8r(bfr[j], kf);
                        ksp[j] += ((kf[0] + kf[1]) + (kf[2] + kf[3]))
                                + ((kf[4] + kf[5]) + (kf[6] + kf[7]));
                    }
                }
                #pragma unroll
                for (int j = 0; j < 4; ++j)
                    acc[j] = __builtin_amdgcn_mfma_f32_16x16x32_bf16(bfr[j], af, acc[j], 0, 0, 0);
            }
        }
    }

    float* kp = KVp + ((long)split * 64 + bh) * 4096;
    const int q4 = lq * 4;
    #pragma unroll
    for (int j = 0; j < 4; ++j)
        *(f32x4*)(kp + vrow * 64 + 16 * j + q4) = acc[j];

    if (wave == 0) {
        #pragma unroll
        for (int j = 0; j < 4; ++j) {
            float s = ksp[j];
            s += __shfl_xor(s, 16);
            s += __shfl_xor(s, 32);
            if (lane < 16)
                Ksump[((long)split * 64 + bh) * 64 + 16 * j + lr] = s;
        }
    }
}

// ---------------- kernel 3b: fold partials -> KV bf16 + Ksum f32 ----------
__global__ __launch_bounds__(256) void kv_final(
    const float* __restrict__ KVp, const float* __restrict__ Ksump,
    unsigned short* __restrict__ KVb, float* __restrict__ Ksum)
{
    int bh = blockIdx.x, t = threadIdx.x;
    float s[16];
    #pragma unroll
    for (int g = 0; g < 16; ++g) s[g] = 0.f;
    for (int sp = 0; sp < KVSPLITS; ++sp) {
        const float* src = KVp + ((long)sp * 64 + bh) * 4096 + t * 16;
        #pragma unroll
        for (int g = 0; g < 4; ++g) {
            float4 v = *(const float4*)(src + g * 4);
            s[g * 4 + 0] += v.x; s[g * 4 + 1] += v.y;
            s[g * 4 + 2] += v.z; s[g * 4 + 3] += v.w;
        }
    }
    uint4 o0, o1;
    o0.x = pk2(s[0], s[1]);  o0.y = pk2(s[2], s[3]);
    o0.z = pk2(s[4], s[5]);  o0.w = pk2(s[6], s[7]);
    o1.x = pk2(s[8], s[9]);  o1.y = pk2(s[10], s[11]);
    o1.z = pk2(s[12], s[13]); o1.w = pk2(s[14], s[15]);
    *(uint4*)(KVb + (long)bh * 4096 + t * 16) = o0;
    *(uint4*)(KVb + (long)bh * 4096 + t * 16 + 8) = o1;
    if (t < 16) {
        float4 a = {0.f, 0.f, 0.f, 0.f};
        for (int p = 0; p < KVSPLITS; p += 4) {
            #pragma unroll
            for (int q = 0; q < 4; ++q) {
                float4 v = *(const float4*)(Ksump + ((long)(p + q) * 64 + bh) * 64 + t * 4);
                a.x += v.x; a.y += v.y; a.z += v.z; a.w += v.w;
            }
        }
        *(float4*)(Ksum + bh * 64 + t * 4) = a;
    }
}

// ---------------- kernel 4: numerator MFMA + fused denominator -> attn bf16
__global__ __launch_bounds__(256) void attn_kernel(
    const unsigned short* __restrict__ Qb, const unsigned short* __restrict__ KVb,
    const float* __restrict__ Ksum, const float* __restrict__ stdp,
    unsigned short* __restrict__ attn)
{
    __shared__ unsigned short Cs[256 * 72];   // output staging
    int t = threadIdx.x;
    int bh = blockIdx.y;   // 64
    int b = bh >> 4, h = bh & 15;

    int wave = t >> 6, lane = t & 63, lr = lane & 15, lk = (lane >> 4) * 8;
    const unsigned short* kvb = KVb + (long)bh * 4096;
    const float* ksb = Ksum + bh * 64;

    // hoist KV fragments + Ksum slices (block-invariant)
    bf16x8 bfrh[2][4];
    float ksf[2][8];
    #pragma unroll
    for (int s = 0; s < 2; ++s) {
        #pragma unroll
        for (int j = 0; j < 4; ++j)
            bfrh[s][j] = *(const bf16x8*)(kvb + (16 * j + lr) * 64 + s * 32 + lk);
        float4 ka = *(const float4*)(ksb + s * 32 + lk);
        float4 kb2 = *(const float4*)(ksb + s * 32 + lk + 4);
        ksf[s][0] = ka.x; ksf[s][1] = ka.y; ksf[s][2] = ka.z; ksf[s][3] = ka.w;
        ksf[s][4] = kb2.x; ksf[s][5] = kb2.y; ksf[s][6] = kb2.z; ksf[s][7] = kb2.w;
    }
    float sg = 1.f / (1.f + __expf(-stdp[h]));
    int q4 = (lane >> 4) * 4;

    for (int c = 0; c < 2; ++c) {
        int rc = blockIdx.x * 2 + c;
        int rowbase = rc * 256 + wave * 64;

        f32x4 acc[4][4];
        #pragma unroll
        for (int i = 0; i < 4; ++i)
            #pragma unroll
            for (int j = 0; j < 4; ++j) acc[i][j] = (f32x4){0.f, 0.f, 0.f, 0.f};
        float ds[4] = {0.f, 0.f, 0.f, 0.f};

        #pragma unroll
        for (int s = 0; s < 2; ++s) {
            bf16x8 af[4];
            #pragma unroll
            for (int i = 0; i < 4; ++i)
                af[i] = *(const bf16x8*)(Qb + ((long)bh * SEQLEN + rowbase + 16 * i + lr) * 64 + s * 32 + lk);
            #pragma unroll
            for (int i = 0; i < 4; ++i) {
                float qf[8]; unp8r(af[i], qf);
                #pragma unroll
                for (int e = 0; e < 8; ++e) ds[i] += qf[e] * ksf[s][e];
            }
            #pragma unroll
            for (int i = 0; i < 4; ++i)
                #pragma unroll
                for (int j = 0; j < 4; ++j)
                    acc[i][j] = __builtin_amdgcn_mfma_f32_16x16x32_bf16(bfrh[s][j], af[i], acc[i][j], 0, 0, 0);
        }

        float dinv_i[4];
        #pragma unroll
        for (int i = 0; i < 4; ++i) {
            float d = ds[i];
            d += __shfl_xor(d, 16);
            d += __shfl_xor(d, 32);
            dinv_i[i] = sg / (d + 1e-6f);
        }

        #pragma unroll
        for (int j = 0; j < 4; ++j) {
            int v0c = 16 * j + q4;
            #pragma unroll
            for (int i = 0; i < 4; ++i) {
                int row = wave * 64 + 16 * i + lr;
                float d = dinv_i[i];
                uint2 pkd;
                pkd.x = pk2(acc[i][j][0] * d, acc[i][j][1] * d);
                pkd.y = pk2(acc[i][j][2] * d, acc[i][j][3] * d);
                *(uint2*)(Cs + row * 72 + v0c) = pkd;
            }
        }
        __syncthreads();
        #pragma unroll
        for (int u = 0; u < 8; ++u) {
            int row = u * 32 + (t >> 3);
            int nn = rc * 256 + row;
            long a = ((long)(b * SEQLEN + nn)) * DIMSZ + h * 64 + (t & 7) * 8;
            *(uint4*)(attn + a) = *(const uint4*)(Cs + row * 72 + (t & 7) * 8);
        }
        __syncthreads();   // Cs reuse across chunks
    }
}

// ---------------- kernel 5: output GEMM — 256x256 tile, 16 waves ----------
__global__ __launch_bounds__(1024, 1) void out_gemm8(
    const unsigned short* __restrict__ A, const unsigned short* __restrict__ W,
    const float* __restrict__ bo, float* __restrict__ out)
{
    __shared__ __align__(16) char SM[131072];
    const int t = threadIdx.x;
    const int wave = t >> 6, lane = t & 63;
    const int lr = lane & 15, lq = lane >> 4;
    const int wm = wave >> 2, wn = wave & 3;
    const int m0 = blockIdx.x * 256;
    const int c0 = blockIdx.y * 256;

    const int sc = (((t & 7) ^ ((t >> 3) & 7)) * 8);
    const unsigned short* pA = A + (long)(m0 + (t >> 3)) * DIMSZ + sc;
    const unsigned short* pB = W + (long)(c0 + (t >> 3)) * DIMSZ + sc;
    char* ldsW = SM + wave * 1024;

    const int xo = ((lq ^ (lr & 7)) << 4);
    const char* ABase = SM + wm * 8192 + lr * 128;
    const char* BBase = SM + 32768 + (wn * 64 + lr) * 128;

    f32x4 acc[4][4];
    #pragma unroll
    for (int i = 0; i < 4; ++i)
        #pragma unroll
        for (int j = 0; j < 4; ++j) acc[i][j] = (f32x4){0.f, 0.f, 0.f, 0.f};

#define STAGE(Q, O) do {                                                        \
        if ((Q) < 16) {                                                         \
            const int isB_ = ((O) < 2) ? 1 : 0;                                 \
            const int half_ = isB_ ? (O) : ((O) - 2);                           \
            const unsigned short* s_ = (isB_ ? pB : pA)                         \
                                       + (long)half_ * 131072 + (Q) * 64;       \
            char* d_ = ldsW + (((Q) & 1) << 16) + isB_ * 32768 + half_ * 16384; \
            async16(s_, d_);                                                    \
        }                                                                       \
    } while (0)

    STAGE(0, 0); STAGE(0, 1); STAGE(0, 2); STAGE(0, 3);
    STAGE(1, 0); STAGE(1, 1); STAGE(1, 2);
    asm volatile("s_waitcnt vmcnt(3)" ::: "memory");
    __builtin_amdgcn_s_barrier();

    for (int kt = 0; kt < 16; ++kt) {
        const int buf = (kt & 1) << 16;
        bf16x8 a[4], b[4];

        // K-half 0
        b[0] = *(const bf16x8*)(BBase + buf + 0 * 2048 + xo);
        b[1] = *(const bf16x8*)(BBase + buf + 1 * 2048 + xo);
        #pragma unroll
        for (int i = 0; i < 4; ++i)
            a[i] = *(const bf16x8*)(ABase + buf + i * 2048 + xo);
        __builtin_amdgcn_sched_barrier(0);
        b[2] = *(const bf16x8*)(BBase + buf + 2 * 2048 + xo);
        b[3] = *(const bf16x8*)(BBase + buf + 3 * 2048 + xo);
        __builtin_amdgcn_sched_barrier(0);
        STAGE(kt + 1, 3);

        asm volatile("s_waitcnt lgkmcnt(2)" ::: "memory");
        __builtin_amdgcn_sched_barrier(0);
        __builtin_amdgcn_s_setprio(1);
        #pragma unroll
        for (int i = 0; i < 4; ++i)
            #pragma unroll
            for (int j = 0; j < 2; ++j)
                acc[i][j] = __builtin_amdgcn_mfma_f32_16x16x32_bf16(
                    b[j], a[i], acc[i][j], 0, 0, 0);
        __builtin_amdgcn_s_setprio(0);

        asm volatile("s_waitcnt lgkmcnt(0)" ::: "memory");
        __builtin_amdgcn_sched_barrier(0);
        __builtin_amdgcn_s_setprio(1);
        #pragma unroll
        for (int i = 0; i < 4; ++i)
            #pragma unroll
            for (int j = 2; j < 4; ++j)
                acc[i][j] = __builtin_amdgcn_mfma_f32_16x16x32_bf16(
                    b[j], a[i], acc[i][j], 0, 0, 0);
        __builtin_amdgcn_s_setprio(0);

        // K-half 1
        b[0] = *(const bf16x8*)(BBase + buf + 0 * 2048 + (xo ^ 64));
        b[1] = *(const bf16x8*)(BBase + buf + 1 * 2048 + (xo ^ 64));
        #pragma unroll
        for (int i = 0; i < 4; ++i)
            a[i] = *(const bf16x8*)(ABase + buf + i * 2048 + (xo ^ 64));
        __builtin_amdgcn_sched_barrier(0);
        b[2] = *(const bf16x8*)(BBase + buf + 2 * 2048 + (xo ^ 64));
        b[3] = *(const bf16x8*)(BBase + buf + 3 * 2048 + (xo ^ 64));
        __builtin_amdgcn_sched_barrier(0);

        asm volatile("s_waitcnt lgkmcnt(2)" ::: "memory");
        __builtin_amdgcn_sched_barrier(0);
        __builtin_amdgcn_s_setprio(1);
        #pragma unroll
        for (int i = 0; i < 4; ++i)
            #pragma unroll
            for (int j = 0; j < 2; ++j)
                acc[i][j] = __builtin_amdgcn_mfma_f32_16x16x32_bf16(
                    b[j], a[i], acc[i][j], 0, 0, 0);
        __builtin_amdgcn_s_setprio(0);

        asm volatile("s_waitcnt lgkmcnt(0)" ::: "memory");
        __builtin_amdgcn_sched_barrier(0);
        __builtin_amdgcn_s_barrier();
        STAGE(kt + 2, 0); STAGE(kt + 2, 1); STAGE(kt + 2, 2);

        __builtin_amdgcn_s_setprio(1);
        #pragma unroll
        for (int i = 0; i < 4; ++i)
            #pragma unroll
            for (int j = 2; j < 4; ++j)
                acc[i][j] = __builtin_amdgcn_mfma_f32_16x16x32_bf16(
                    b[j], a[i], acc[i][j], 0, 0, 0);
        __builtin_amdgcn_s_setprio(0);

        if (kt < 14)       asm volatile("s_waitcnt vmcnt(3)" ::: "memory");
        else if (kt == 14) asm volatile("s_waitcnt vmcnt(0)" ::: "memory");
        __builtin_amdgcn_s_barrier();
    }
#undef STAGE

    const int q4 = lq * 4;
    #pragma unroll
    for (int j = 0; j < 4; ++j) {
        const int c = c0 + wn * 64 + 16 * j + q4;
        const float4 b4 = *(const float4*)(bo + c);
        #pragma unroll
        for (int i = 0; i < 4; ++i) {
            const int gm = m0 + wm * 64 + 16 * i + lr;
            float4 v;
            v.x = acc[i][j][0] + b4.x; v.y = acc[i][j][1] + b4.y;
            v.z = acc[i][j][2] + b4.z; v.w = acc[i][j][3] + b4.w;
            *(float4*)(out + (long)gm * DIMSZ + c) = v;
        }
    }
}

extern "C" void kernel_launch(void* const* d_in, const int* in_sizes, int n_in,
                              void* d_out, int out_size, void* d_ws, size_t ws_size,
                              hipStream_t stream) {
    const float* x    = (const float*)d_in[0];
    const float* Wq   = (const float*)d_in[1];
    const float* bq   = (const float*)d_in[2];
    const float* Wk   = (const float*)d_in[3];
    const float* bk   = (const float*)d_in[4];
    const float* Wv   = (const float*)d_in[5];
    const float* bv   = (const float*)d_in[6];
    const float* Wo   = (const float*)d_in[7];
    const float* bo   = (const float*)d_in[8];
    const float* stdp = (const float*)d_in[9];
    float* out = (float*)d_out;

    char* ws = (char*)d_ws;
    unsigned short* xb   = (unsigned short*)(ws);
    float*          KVp  = (float*)(ws);                          // 8.4 MB
    unsigned short* attn = (unsigned short*)(ws);                 // 32 MB
    unsigned short* Wqkv = (unsigned short*)(ws + 33554432L);     // 6 MB
    float*          Ksump= (float*)(ws + 33554432L);              // 128 KB
    unsigned short* KVb  = (unsigned short*)(ws + 33816576L);     // 512 KB
    float*          Ksum = (float*)(ws + 34340864L);              // 16 KB
    unsigned short* Wob  = (unsigned short*)(ws + 39845888L);     // 2 MB
    unsigned short* Qb   = (unsigned short*)(ws + 41943040L);     // 32 MB
    unsigned short* Kb   = (unsigned short*)(ws + 75497472L);     // 32 MB
    unsigned short* Vb   = (unsigned short*)(ws + 109051904L);    // 32 MB

    cast_pack<<<20480, 256, 0, stream>>>(x, Wq, Wk, Wv, Wo, stdp, xb, Wqkv, Wob,
                                         out + 16777216L);
    qkv_gemm8<<<dim3(64, 12), 1024, 0, stream>>>(xb, Wqkv, bq, bk, bv, Qb, Kb, Vb);
    kv_reduce<<<dim3(64, KVSPLITS), 256, 0, stream>>>(Kb, Vb, KVp, Ksump);
    kv_final<<<64, 256, 0, stream>>>(KVp, Ksump, KVb, Ksum);
    attn_kernel<<<dim3(8, 64), 256, 0, stream>>>(Qb, KVb, Ksum, stdp, attn);
    out_gemm8<<<dim3(64, 4), 1024, 0, stream>>>(attn, Wob, bo, out);
}

// Round 10
// 310.479 us; speedup vs baseline: 9.3455x; 1.4384x over previous
//
#include <hip/hip_runtime.h>
#include <hip/hip_bf16.h>

#define DIMSZ 1024
#define SEQLEN 4096
#define NHEAD 16
#define NX 16777216L     // x elements
#define NW 1048576L      // weight elements each
#define KVSPLITS 8

typedef __attribute__((ext_vector_type(8))) short bf16x8;
typedef __attribute__((ext_vector_type(4))) float f32x4;

__device__ __forceinline__ unsigned short f2bf(float f) {
    union { float f; unsigned int i; } c; c.f = f;
    unsigned int x = c.i;
    unsigned int r = (x + 0x7fffu + ((x >> 16) & 1u)) >> 16;
    return (unsigned short)r;
}

// pack two f32 -> two bf16 (round-half-up) in one perm
__device__ __forceinline__ unsigned int pk2(float lo, float hi) {
    union { float f; unsigned int i; } a, b; a.f = lo; b.f = hi;
    return __builtin_amdgcn_perm(b.i + 0x8000u, a.i + 0x8000u, 0x07060302u);
}

// register-resident bf16x8 -> 8 floats
__device__ __forceinline__ void unp8r(bf16x8 v, float* f) {
    union { bf16x8 s; uint4 w; } u; u.s = v;
    union { unsigned int i; float f; } c;
    c.i = u.w.x << 16;           f[0] = c.f;
    c.i = u.w.x & 0xffff0000u;   f[1] = c.f;
    c.i = u.w.y << 16;           f[2] = c.f;
    c.i = u.w.y & 0xffff0000u;   f[3] = c.f;
    c.i = u.w.z << 16;           f[4] = c.f;
    c.i = u.w.z & 0xffff0000u;   f[5] = c.f;
    c.i = u.w.w << 16;           f[6] = c.f;
    c.i = u.w.w & 0xffff0000u;   f[7] = c.f;
}

__device__ __forceinline__ void async16(const void* g, void* l) {
    __builtin_amdgcn_global_load_lds(
        (const __attribute__((address_space(1))) void*)g,
        (__attribute__((address_space(3))) void*)l,
        16, 0, 0);
}

// ---------------- kernel 1: casts + weight packing + stdp passthrough ------
// grid-stride (G11): 2048 blocks, ~10 iters each; BW-bound.
__global__ __launch_bounds__(256) void cast_pack(
    const float* __restrict__ x, const float* __restrict__ Wq,
    const float* __restrict__ Wk, const float* __restrict__ Wv,
    const float* __restrict__ Wo, const float* __restrict__ stdp,
    unsigned short* __restrict__ xb, unsigned short* __restrict__ Wqkv,
    unsigned short* __restrict__ Wob, float* __restrict__ outTail)
{
    const long total = (NX + 4 * NW) / 4;   // quads
    for (long q = (long)blockIdx.x * 256 + threadIdx.x; q < total;
         q += (long)gridDim.x * 256) {
        long i4 = q * 4;
        const float* src; unsigned short* dst; long off;
        if (i4 < NX)               { src = x;  dst = xb;          off = i4; }
        else if (i4 < NX + NW)     { src = Wq; dst = Wqkv;        off = i4 - NX; }
        else if (i4 < NX + 2*NW)   { src = Wk; dst = Wqkv + NW;   off = i4 - NX - NW; }
        else if (i4 < NX + 3*NW)   { src = Wv; dst = Wqkv + 2*NW; off = i4 - NX - 2*NW; }
        else                       { src = Wo; dst = Wob;         off = i4 - NX - 3*NW; }
        float4 v = *(const float4*)(src + off);
        union { unsigned short u[4]; uint2 p; } o;
        o.u[0] = f2bf(v.x); o.u[1] = f2bf(v.y); o.u[2] = f2bf(v.z); o.u[3] = f2bf(v.w);
        *(uint2*)(dst + off) = o.p;
    }
    if (blockIdx.x == 0 && threadIdx.x < NHEAD) outTail[threadIdx.x] = stdp[threadIdx.x];
}

// ---------------- kernel 2: fused QKV GEMM — 256x256 tile, 16 waves --------
// (R7 known-good: 103 µs, ~1000 TF.) 1024 threads / 16 waves (4M x 4N,
// 64x64/wave): acc in AGPRs, 4 waves/SIMD. Counted-lgkm gates per K-half;
// frags re-read per half to cap liveness. vm stream: O3(kt+1) in half0;
// O0-2(kt+2) after the read-complete barrier; vmcnt(3) at kt end == kt+1
// fully landed. R8/R9 hybrid-A designs are infeasible: a single vmcnt can't
// separate A-loads from B-stage drains, and the reg-dbuf fix needs >128 VGPR.
__global__ __launch_bounds__(1024, 1) void qkv_gemm8(
    const unsigned short* __restrict__ A, const unsigned short* __restrict__ W,
    const float* __restrict__ bq, const float* __restrict__ bk,
    const float* __restrict__ bv,
    unsigned short* __restrict__ Qb, unsigned short* __restrict__ Kb,
    unsigned short* __restrict__ Vb)
{
    __shared__ __align__(16) char SM[131072];   // 2 bufs x (A 32K + B 32K); reused by epilogue
    const int t = threadIdx.x;
    const int wave = t >> 6, lane = t & 63;
    const int lr = lane & 15, lq = lane >> 4;
    const int wm = wave >> 2, wn = wave & 3;    // wm,wn in 0..3
    const int m0 = blockIdx.x * 256;
    const int c0 = blockIdx.y * 256;

    // staging: LDS dest is linear (global_load_lds), so swizzle the SOURCE chunk.
    const int sc = (((t & 7) ^ ((t >> 3) & 7)) * 8);
    const unsigned short* pA = A + (long)(m0 + (t >> 3)) * DIMSZ + sc;
    const unsigned short* pB = W + (long)(c0 + (t >> 3)) * DIMSZ + sc;
    char* ldsW = SM + wave * 1024;  // wave-uniform lane base (lane*16 added by HW)

    // ds_read swizzle: frag (row, kchunk = s*4+lq) lives at chunk (kchunk ^ (lr&7))
    const int xo = ((lq ^ (lr & 7)) << 4);
    const char* ABase = SM + wm * 8192 + lr * 128;             // rows wm*64+16i+lr
    const char* BBase = SM + 32768 + (wn * 64 + lr) * 128;     // rows wn*64+16j+lr

    f32x4 acc[4][4];
    #pragma unroll
    for (int i = 0; i < 4; ++i)
        #pragma unroll
        for (int j = 0; j < 4; ++j) acc[i][j] = (f32x4){0.f, 0.f, 0.f, 0.f};

    // one async16 (1024 thr x 16B = 16KB) per piece; O: 0,1=B half, 2,3=A half
#define STAGE(Q, O) do {                                                        \
        if ((Q) < 16) {                                                         \
            const int isB_ = ((O) < 2) ? 1 : 0;                                 \
            const int half_ = isB_ ? (O) : ((O) - 2);                           \
            const unsigned short* s_ = (isB_ ? pB : pA)                         \
                                       + (long)half_ * 131072 + (Q) * 64;       \
            char* d_ = ldsW + (((Q) & 1) << 16) + isB_ * 32768 + half_ * 16384; \
            async16(s_, d_);                                                    \
        }                                                                       \
    } while (0)

    // prologue: kt0 all 4 pieces + kt1 pieces 0-2 (7 vm-ops)
    STAGE(0, 0); STAGE(0, 1); STAGE(0, 2); STAGE(0, 3);
    STAGE(1, 0); STAGE(1, 1); STAGE(1, 2);
    asm volatile("s_waitcnt vmcnt(3)" ::: "memory");   // kt0 fully landed
    __builtin_amdgcn_s_barrier();

    for (int kt = 0; kt < 16; ++kt) {
        const int buf = (kt & 1) << 16;
        bf16x8 a[4], b[4];

        // ================= K-half 0 (chunks lq) =================
        b[0] = *(const bf16x8*)(BBase + buf + 0 * 2048 + xo);
        b[1] = *(const bf16x8*)(BBase + buf + 1 * 2048 + xo);
        #pragma unroll
        for (int i = 0; i < 4; ++i)
            a[i] = *(const bf16x8*)(ABase + buf + i * 2048 + xo);
        __builtin_amdgcn_sched_barrier(0);
        b[2] = *(const bf16x8*)(BBase + buf + 2 * 2048 + xo);
        b[3] = *(const bf16x8*)(BBase + buf + 3 * 2048 + xo);
        __builtin_amdgcn_sched_barrier(0);
        STAGE(kt + 1, 3);                        // A-half1 of next tile (other parity)

        asm volatile("s_waitcnt lgkmcnt(2)" ::: "memory");   // b0,b1,a0-3 done
        __builtin_amdgcn_sched_barrier(0);
        __builtin_amdgcn_s_setprio(1);
        #pragma unroll
        for (int i = 0; i < 4; ++i)
            #pragma unroll
            for (int j = 0; j < 2; ++j)
                acc[i][j] = __builtin_amdgcn_mfma_f32_16x16x32_bf16(
                    b[j], a[i], acc[i][j], 0, 0, 0);
        __builtin_amdgcn_s_setprio(0);

        asm volatile("s_waitcnt lgkmcnt(0)" ::: "memory");   // b2,b3 done
        __builtin_amdgcn_sched_barrier(0);
        __builtin_amdgcn_s_setprio(1);
        #pragma unroll
        for (int i = 0; i < 4; ++i)
            #pragma unroll
            for (int j = 2; j < 4; ++j)
                acc[i][j] = __builtin_amdgcn_mfma_f32_16x16x32_bf16(
                    b[j], a[i], acc[i][j], 0, 0, 0);
        __builtin_amdgcn_s_setprio(0);

        // ================= K-half 1 (chunks 4+lq -> xo^64) =================
        b[0] = *(const bf16x8*)(BBase + buf + 0 * 2048 + (xo ^ 64));
        b[1] = *(const bf16x8*)(BBase + buf + 1 * 2048 + (xo ^ 64));
        #pragma unroll
        for (int i = 0; i < 4; ++i)
            a[i] = *(const bf16x8*)(ABase + buf + i * 2048 + (xo ^ 64));
        __builtin_amdgcn_sched_barrier(0);
        b[2] = *(const bf16x8*)(BBase + buf + 2 * 2048 + (xo ^ 64));
        b[3] = *(const bf16x8*)(BBase + buf + 3 * 2048 + (xo ^ 64));
        __builtin_amdgcn_sched_barrier(0);

        asm volatile("s_waitcnt lgkmcnt(2)" ::: "memory");
        __builtin_amdgcn_sched_barrier(0);
        __builtin_amdgcn_s_setprio(1);
        #pragma unroll
        for (int i = 0; i < 4; ++i)
            #pragma unroll
            for (int j = 0; j < 2; ++j)
                acc[i][j] = __builtin_amdgcn_mfma_f32_16x16x32_bf16(
                    b[j], a[i], acc[i][j], 0, 0, 0);
        __builtin_amdgcn_s_setprio(0);

        asm volatile("s_waitcnt lgkmcnt(0)" ::: "memory");   // ALL reads of buf done
        __builtin_amdgcn_sched_barrier(0);
        __builtin_amdgcn_s_barrier();            // all waves done reading this buf
        STAGE(kt + 2, 0); STAGE(kt + 2, 1); STAGE(kt + 2, 2);  // overwrite B0,B1,A0

        // last quadrant: register-only; hides the stage issue
        __builtin_amdgcn_s_setprio(1);
        #pragma unroll
        for (int i = 0; i < 4; ++i)
            #pragma unroll
            for (int j = 2; j < 4; ++j)
                acc[i][j] = __builtin_amdgcn_mfma_f32_16x16x32_bf16(
                    b[j], a[i], acc[i][j], 0, 0, 0);
        __builtin_amdgcn_s_setprio(0);

        if (kt < 14)       asm volatile("s_waitcnt vmcnt(3)" ::: "memory");
        else if (kt == 14) asm volatile("s_waitcnt vmcnt(0)" ::: "memory");
        __builtin_amdgcn_s_barrier();
    }
#undef STAGE

    // ---- epilogue: bias + elu+1 + pack, swizzled LDS transpose, stores ----
    const int proj = c0 >> 10;                         // block-uniform
    const float* bias = proj == 0 ? bq : (proj == 1 ? bk : bv);
    const bool qk = proj < 2;
    const int cb = (c0 & 1023) + wn * 64;
    const int q4 = lq * 4;
    #pragma unroll
    for (int j = 0; j < 4; ++j) {
        const float4 b4 = *(const float4*)(bias + cb + 16 * j + q4);
        #pragma unroll
        for (int i = 0; i < 4; ++i) {
            float v0 = acc[i][j][0] + b4.x, v1 = acc[i][j][1] + b4.y;
            float v2 = acc[i][j][2] + b4.z, v3 = acc[i][j][3] + b4.w;
            if (qk) {
                v0 = v0 > 0.f ? v0 + 1.f : __expf(v0);
                v1 = v1 > 0.f ? v1 + 1.f : __expf(v1);
                v2 = v2 > 0.f ? v2 + 1.f : __expf(v2);
                v3 = v3 > 0.f ? v3 + 1.f : __expf(v3);
            }
            const int row = wm * 64 + 16 * i + lr;
            int byte = row * 512 + wn * 128 + j * 32 + q4 * 2;
            byte ^= (row & 7) << 4;
            uint2 pkd; pkd.x = pk2(v0, v1); pkd.y = pk2(v2, v3);
            *(uint2*)(SM + byte) = pkd;
        }
    }
    __syncthreads();
    unsigned short* dstp = proj == 0 ? Qb : (proj == 1 ? Kb : Vb);
    const int colsh = (t & 31) * 8;                    // tile-local col (shorts)
    const int h = ((c0 >> 6) + (colsh >> 6)) & 15;
    const int b_ = m0 >> 12;
    unsigned short* dbase = dstp + ((long)(b_ * 16 + h) * SEQLEN) * 64 + (colsh & 63);
    #pragma unroll
    for (int u = 0; u < 8; ++u) {
        const int flat = u * 16384 + t * 16;
        const int row = flat >> 9;
        uint4 val = *(const uint4*)(SM + (flat ^ ((row & 7) << 4)));
        const int n = (m0 + row) & 4095;
        *(uint4*)(dbase + (long)n * 64) = val;
    }
}

// ---------------- kernel 3: KV partials + Ksum partials via MFMA ----------
// splits=8; each block folds 512 rows in two 256-row LDS passes, accumulator
// carried across. Transposed swizzled staging; swapped-operand mfma.
__global__ __launch_bounds__(256) void kv_reduce(
    const unsigned short* __restrict__ Kb, const unsigned short* __restrict__ Vb,
    float* __restrict__ KVp, float* __restrict__ Ksump)
{
    __shared__ __align__(16) char LDS[65536];   // 2 iters x (Kt 16K + Vt 16K)
    int bh = blockIdx.x, split = blockIdx.y, t = threadIdx.x;
    int wave = t >> 6, lane = t & 63, lr = lane & 15, lq = lane >> 4;

    const int nl = t & 127;            // local n row this thread stages
    const int dh = (t >> 7) * 32;      // d-half (wave-uniform)
    const int vrow = 16 * wave + lr;

    f32x4 acc[4];
    #pragma unroll
    for (int j = 0; j < 4; ++j) acc[j] = (f32x4){0.f, 0.f, 0.f, 0.f};
    float ksp[4] = {0.f, 0.f, 0.f, 0.f};

    for (int half = 0; half < 2; ++half) {
        const unsigned short* Kbase = Kb + ((long)bh * SEQLEN + split * 512 + half * 256) * 64;
        const unsigned short* Vbase = Vb + ((long)bh * SEQLEN + split * 512 + half * 256) * 64;

        union Q2S { uint4 q[4]; unsigned short s[32]; };
        Q2S kq[2], vq[2];
        #pragma unroll
        for (int it = 0; it < 2; ++it) {
            const unsigned short* kp = Kbase + (long)(it * 128 + nl) * 64 + dh;
            const unsigned short* vp = Vbase + (long)(it * 128 + nl) * 64 + dh;
            #pragma unroll
            for (int g = 0; g < 4; ++g) {
                kq[it].q[g] = *(const uint4*)(kp + g * 8);
                vq[it].q[g] = *(const uint4*)(vp + g * 8);
            }
        }
        if (half) __syncthreads();   // prior pass's reads complete before overwrite
        // transposed swizzled stores: elem (n=nl, d=dh+e) at d*256 + (2n ^ ((d&7)<<4))
        #pragma unroll
        for (int it = 0; it < 2; ++it) {
            char* buf = LDS + it * 32768;
            #pragma unroll
            for (int e = 0; e < 32; ++e) {
                const int d = dh + e;
                const int a = d * 256 + ((nl * 2) ^ ((d & 7) << 4));
                *(unsigned short*)(buf + a) = kq[it].s[e];
                *(unsigned short*)(buf + 16384 + a) = vq[it].s[e];
            }
        }
        __syncthreads();

        #pragma unroll
        for (int it = 0; it < 2; ++it) {
            const char* buf = LDS + it * 32768;
            #pragma unroll
            for (int ns = 0; ns < 4; ++ns) {
                const int xoff = (ns * 64 + lq * 16) ^ ((lr & 7) << 4);
                bf16x8 af = *(const bf16x8*)(buf + 16384 + vrow * 256 + xoff);
                bf16x8 bfr[4];
                #pragma unroll
                for (int j = 0; j < 4; ++j)
                    bfr[j] = *(const bf16x8*)(buf + (16 * j + lr) * 256 + xoff);
                if (wave == 0) {
                    #pragma unroll
                    for (int j = 0; j < 4; ++j) {
                        float kf[8]; unp8r(bfr[j], kf);
                        ksp[j] += ((kf[0] + kf[1]) + (kf[2] + kf[3]))
                                + ((kf[4] + kf[5]) + (kf[6] + kf[7]));
                    }
                }
                #pragma unroll
                for (int j = 0; j < 4; ++j)
                    acc[j] = __builtin_amdgcn_mfma_f32_16x16x32_bf16(bfr[j], af, acc[j], 0, 0, 0);
            }
        }
    }

    float* kp = KVp + ((long)split * 64 + bh) * 4096;
    const int q4 = lq * 4;
    #pragma unroll
    for (int j = 0; j < 4; ++j)
        *(f32x4*)(kp + vrow * 64 + 16 * j + q4) = acc[j];

    if (wave == 0) {
        #pragma unroll
        for (int j = 0; j < 4; ++j) {
            float s = ksp[j];
            s += __shfl_xor(s, 16);
            s += __shfl_xor(s, 32);
            if (lane < 16)
                Ksump[((long)split * 64 + bh) * 64 + 16 * j + lr] = s;
        }
    }
}

// ---------------- kernel 3b: fold partials -> KV bf16 + Ksum f32 ----------
__global__ __launch_bounds__(256) void kv_final(
    const float* __restrict__ KVp, const float* __restrict__ Ksump,
    unsigned short* __restrict__ KVb, float* __restrict__ Ksum)
{
    int bh = blockIdx.x, t = threadIdx.x;
    float s[16];
    #pragma unroll
    for (int g = 0; g < 16; ++g) s[g] = 0.f;
    for (int sp = 0; sp < KVSPLITS; ++sp) {
        const float* src = KVp + ((long)sp * 64 + bh) * 4096 + t * 16;
        #pragma unroll
        for (int g = 0; g < 4; ++g) {
            float4 v = *(const float4*)(src + g * 4);
            s[g * 4 + 0] += v.x; s[g * 4 + 1] += v.y;
            s[g * 4 + 2] += v.z; s[g * 4 + 3] += v.w;
        }
    }
    uint4 o0, o1;
    o0.x = pk2(s[0], s[1]);  o0.y = pk2(s[2], s[3]);
    o0.z = pk2(s[4], s[5]);  o0.w = pk2(s[6], s[7]);
    o1.x = pk2(s[8], s[9]);  o1.y = pk2(s[10], s[11]);
    o1.z = pk2(s[12], s[13]); o1.w = pk2(s[14], s[15]);
    *(uint4*)(KVb + (long)bh * 4096 + t * 16) = o0;
    *(uint4*)(KVb + (long)bh * 4096 + t * 16 + 8) = o1;
    if (t < 16) {
        float4 a = {0.f, 0.f, 0.f, 0.f};
        for (int p = 0; p < KVSPLITS; p += 4) {
            #pragma unroll
            for (int q = 0; q < 4; ++q) {
                float4 v = *(const float4*)(Ksump + ((long)(p + q) * 64 + bh) * 64 + t * 4);
                a.x += v.x; a.y += v.y; a.z += v.z; a.w += v.w;
            }
        }
        *(float4*)(Ksum + bh * 64 + t * 4) = a;
    }
}

// ---------------- kernel 4: numerator MFMA + fused denominator -> attn bf16
// grid (8,64): 2 row-chunks per block; KV fragments + Ksum hoisted to regs.
__global__ __launch_bounds__(256) void attn_kernel(
    const unsigned short* __restrict__ Qb, const unsigned short* __restrict__ KVb,
    const float* __restrict__ Ksum, const float* __restrict__ stdp,
    unsigned short* __restrict__ attn)
{
    __shared__ unsigned short Cs[256 * 72];   // output staging
    int t = threadIdx.x;
    int bh = blockIdx.y;   // 64
    int b = bh >> 4, h = bh & 15;

    int wave = t >> 6, lane = t & 63, lr = lane & 15, lk = (lane >> 4) * 8;
    const unsigned short* kvb = KVb + (long)bh * 4096;
    const float* ksb = Ksum + bh * 64;

    // hoist KV fragments + Ksum slices (block-invariant)
    bf16x8 bfrh[2][4];
    float ksf[2][8];
    #pragma unroll
    for (int s = 0; s < 2; ++s) {
        #pragma unroll
        for (int j = 0; j < 4; ++j)
            bfrh[s][j] = *(const bf16x8*)(kvb + (16 * j + lr) * 64 + s * 32 + lk);
        float4 ka = *(const float4*)(ksb + s * 32 + lk);
        float4 kb2 = *(const float4*)(ksb + s * 32 + lk + 4);
        ksf[s][0] = ka.x; ksf[s][1] = ka.y; ksf[s][2] = ka.z; ksf[s][3] = ka.w;
        ksf[s][4] = kb2.x; ksf[s][5] = kb2.y; ksf[s][6] = kb2.z; ksf[s][7] = kb2.w;
    }
    float sg = 1.f / (1.f + __expf(-stdp[h]));
    int q4 = (lane >> 4) * 4;

    for (int c = 0; c < 2; ++c) {
        int rc = blockIdx.x * 2 + c;
        int rowbase = rc * 256 + wave * 64;

        f32x4 acc[4][4];
        #pragma unroll
        for (int i = 0; i < 4; ++i)
            #pragma unroll
            for (int j = 0; j < 4; ++j) acc[i][j] = (f32x4){0.f, 0.f, 0.f, 0.f};
        float ds[4] = {0.f, 0.f, 0.f, 0.f};

        #pragma unroll
        for (int s = 0; s < 2; ++s) {
            bf16x8 af[4];
            #pragma unroll
            for (int i = 0; i < 4; ++i)
                af[i] = *(const bf16x8*)(Qb + ((long)bh * SEQLEN + rowbase + 16 * i + lr) * 64 + s * 32 + lk);
            #pragma unroll
            for (int i = 0; i < 4; ++i) {
                float qf[8]; unp8r(af[i], qf);
                #pragma unroll
                for (int e = 0; e < 8; ++e) ds[i] += qf[e] * ksf[s][e];
            }
            #pragma unroll
            for (int i = 0; i < 4; ++i)
                #pragma unroll
                for (int j = 0; j < 4; ++j)
                    acc[i][j] = __builtin_amdgcn_mfma_f32_16x16x32_bf16(bfrh[s][j], af[i], acc[i][j], 0, 0, 0);
        }

        float dinv_i[4];
        #pragma unroll
        for (int i = 0; i < 4; ++i) {
            float d = ds[i];
            d += __shfl_xor(d, 16);
            d += __shfl_xor(d, 32);
            dinv_i[i] = sg / (d + 1e-6f);
        }

        #pragma unroll
        for (int j = 0; j < 4; ++j) {
            int v0c = 16 * j + q4;
            #pragma unroll
            for (int i = 0; i < 4; ++i) {
                int row = wave * 64 + 16 * i + lr;
                float d = dinv_i[i];
                uint2 pkd;
                pkd.x = pk2(acc[i][j][0] * d, acc[i][j][1] * d);
                pkd.y = pk2(acc[i][j][2] * d, acc[i][j][3] * d);
                *(uint2*)(Cs + row * 72 + v0c) = pkd;
            }
        }
        __syncthreads();
        #pragma unroll
        for (int u = 0; u < 8; ++u) {
            int row = u * 32 + (t >> 3);
            int nn = rc * 256 + row;
            long a = ((long)(b * SEQLEN + nn)) * DIMSZ + h * 64 + (t & 7) * 8;
            *(uint4*)(attn + a) = *(const uint4*)(Cs + row * 72 + (t & 7) * 8);
        }
        __syncthreads();   // Cs reuse across chunks
    }
}

// ---------------- kernel 5: output GEMM — 256x256 tile, 16 waves ----------
// same 16-wave counted-lgkm structure as qkv_gemm8; epilogue = +bias, f32.
__global__ __launch_bounds__(1024, 1) void out_gemm8(
    const unsigned short* __restrict__ A, const unsigned short* __restrict__ W,
    const float* __restrict__ bo, float* __restrict__ out)
{
    __shared__ __align__(16) char SM[131072];
    const int t = threadIdx.x;
    const int wave = t >> 6, lane = t & 63;
    const int lr = lane & 15, lq = lane >> 4;
    const int wm = wave >> 2, wn = wave & 3;
    const int m0 = blockIdx.x * 256;
    const int c0 = blockIdx.y * 256;

    const int sc = (((t & 7) ^ ((t >> 3) & 7)) * 8);
    const unsigned short* pA = A + (long)(m0 + (t >> 3)) * DIMSZ + sc;
    const unsigned short* pB = W + (long)(c0 + (t >> 3)) * DIMSZ + sc;
    char* ldsW = SM + wave * 1024;

    const int xo = ((lq ^ (lr & 7)) << 4);
    const char* ABase = SM + wm * 8192 + lr * 128;
    const char* BBase = SM + 32768 + (wn * 64 + lr) * 128;

    f32x4 acc[4][4];
    #pragma unroll
    for (int i = 0; i < 4; ++i)
        #pragma unroll
        for (int j = 0; j < 4; ++j) acc[i][j] = (f32x4){0.f, 0.f, 0.f, 0.f};

#define STAGE(Q, O) do {                                                        \
        if ((Q) < 16) {                                                         \
            const int isB_ = ((O) < 2) ? 1 : 0;                                 \
            const int half_ = isB_ ? (O) : ((O) - 2);                           \
            const unsigned short* s_ = (isB_ ? pB : pA)                         \
                                       + (long)half_ * 131072 + (Q) * 64;       \
            char* d_ = ldsW + (((Q) & 1) << 16) + isB_ * 32768 + half_ * 16384; \
            async16(s_, d_);                                                    \
        }                                                                       \
    } while (0)

    STAGE(0, 0); STAGE(0, 1); STAGE(0, 2); STAGE(0, 3);
    STAGE(1, 0); STAGE(1, 1); STAGE(1, 2);
    asm volatile("s_waitcnt vmcnt(3)" ::: "memory");
    __builtin_amdgcn_s_barrier();

    for (int kt = 0; kt < 16; ++kt) {
        const int buf = (kt & 1) << 16;
        bf16x8 a[4], b[4];

        // K-half 0
        b[0] = *(const bf16x8*)(BBase + buf + 0 * 2048 + xo);
        b[1] = *(const bf16x8*)(BBase + buf + 1 * 2048 + xo);
        #pragma unroll
        for (int i = 0; i < 4; ++i)
            a[i] = *(const bf16x8*)(ABase + buf + i * 2048 + xo);
        __builtin_amdgcn_sched_barrier(0);
        b[2] = *(const bf16x8*)(BBase + buf + 2 * 2048 + xo);
        b[3] = *(const bf16x8*)(BBase + buf + 3 * 2048 + xo);
        __builtin_amdgcn_sched_barrier(0);
        STAGE(kt + 1, 3);

        asm volatile("s_waitcnt lgkmcnt(2)" ::: "memory");
        __builtin_amdgcn_sched_barrier(0);
        __builtin_amdgcn_s_setprio(1);
        #pragma unroll
        for (int i = 0; i < 4; ++i)
            #pragma unroll
            for (int j = 0; j < 2; ++j)
                acc[i][j] = __builtin_amdgcn_mfma_f32_16x16x32_bf16(
                    b[j], a[i], acc[i][j], 0, 0, 0);
        __builtin_amdgcn_s_setprio(0);

        asm volatile("s_waitcnt lgkmcnt(0)" ::: "memory");
        __builtin_amdgcn_sched_barrier(0);
        __builtin_amdgcn_s_setprio(1);
        #pragma unroll
        for (int i = 0; i < 4; ++i)
            #pragma unroll
            for (int j = 2; j < 4; ++j)
                acc[i][j] = __builtin_amdgcn_mfma_f32_16x16x32_bf16(
                    b[j], a[i], acc[i][j], 0, 0, 0);
        __builtin_amdgcn_s_setprio(0);

        // K-half 1
        b[0] = *(const bf16x8*)(BBase + buf + 0 * 2048 + (xo ^ 64));
        b[1] = *(const bf16x8*)(BBase + buf + 1 * 2048 + (xo ^ 64));
        #pragma unroll
        for (int i = 0; i < 4; ++i)
            a[i] = *(const bf16x8*)(ABase + buf + i * 2048 + (xo ^ 64));
        __builtin_amdgcn_sched_barrier(0);
        b[2] = *(const bf16x8*)(BBase + buf + 2 * 2048 + (xo ^ 64));
        b[3] = *(const bf16x8*)(BBase + buf + 3 * 2048 + (xo ^ 64));
        __builtin_amdgcn_sched_barrier(0);

        asm volatile("s_waitcnt lgkmcnt(2)" ::: "memory");
        __builtin_amdgcn_sched_barrier(0);
        __builtin_amdgcn_s_setprio(1);
        #pragma unroll
        for (int i = 0; i < 4; ++i)
            #pragma unroll
            for (int j = 0; j < 2; ++j)
                acc[i][j] = __builtin_amdgcn_mfma_f32_16x16x32_bf16(
                    b[j], a[i], acc[i][j], 0, 0, 0);
        __builtin_amdgcn_s_setprio(0);

        asm volatile("s_waitcnt lgkmcnt(0)" ::: "memory");
        __builtin_amdgcn_sched_barrier(0);
        __builtin_amdgcn_s_barrier();
        STAGE(kt + 2, 0); STAGE(kt + 2, 1); STAGE(kt + 2, 2);

        __builtin_amdgcn_s_setprio(1);
        #pragma unroll
        for (int i = 0; i < 4; ++i)
            #pragma unroll
            for (int j = 2; j < 4; ++j)
                acc[i][j] = __builtin_amdgcn_mfma_f32_16x16x32_bf16(
                    b[j], a[i], acc[i][j], 0, 0, 0);
        __builtin_amdgcn_s_setprio(0);

        if (kt < 14)       asm volatile("s_waitcnt vmcnt(3)" ::: "memory");
        else if (kt == 14) asm volatile("s_waitcnt vmcnt(0)" ::: "memory");
        __builtin_amdgcn_s_barrier();
    }
#undef STAGE

    const int q4 = lq * 4;
    #pragma unroll
    for (int j = 0; j < 4; ++j) {
        const int c = c0 + wn * 64 + 16 * j + q4;
        const float4 b4 = *(const float4*)(bo + c);
        #pragma unroll
        for (int i = 0; i < 4; ++i) {
            const int gm = m0 + wm * 64 + 16 * i + lr;
            float4 v;
            v.x = acc[i][j][0] + b4.x; v.y = acc[i][j][1] + b4.y;
            v.z = acc[i][j][2] + b4.z; v.w = acc[i][j][3] + b4.w;
            *(float4*)(out + (long)gm * DIMSZ + c) = v;
        }
    }
}

extern "C" void kernel_launch(void* const* d_in, const int* in_sizes, int n_in,
                              void* d_out, int out_size, void* d_ws, size_t ws_size,
                              hipStream_t stream) {
    const float* x    = (const float*)d_in[0];
    const float* Wq   = (const float*)d_in[1];
    const float* bq   = (const float*)d_in[2];
    const float* Wk   = (const float*)d_in[3];
    const float* bk   = (const float*)d_in[4];
    const float* Wv   = (const float*)d_in[5];
    const float* bv   = (const float*)d_in[6];
    const float* Wo   = (const float*)d_in[7];
    const float* bo   = (const float*)d_in[8];
    const float* stdp = (const float*)d_in[9];
    float* out = (float*)d_out;

    char* ws = (char*)d_ws;
    unsigned short* xb   = (unsigned short*)(ws);
    float*          KVp  = (float*)(ws);                          // 8.4 MB
    unsigned short* attn = (unsigned short*)(ws);                 // 32 MB
    unsigned short* Wqkv = (unsigned short*)(ws + 33554432L);     // 6 MB
    float*          Ksump= (float*)(ws + 33554432L);              // 128 KB
    unsigned short* KVb  = (unsigned short*)(ws + 33816576L);     // 512 KB
    float*          Ksum = (float*)(ws + 34340864L);              // 16 KB
    unsigned short* Wob  = (unsigned short*)(ws + 39845888L);     // 2 MB
    unsigned short* Qb   = (unsigned short*)(ws + 41943040L);     // 32 MB
    unsigned short* Kb   = (unsigned short*)(ws + 75497472L);     // 32 MB
    unsigned short* Vb   = (unsigned short*)(ws + 109051904L);    // 32 MB

    cast_pack<<<2048, 256, 0, stream>>>(x, Wq, Wk, Wv, Wo, stdp, xb, Wqkv, Wob,
                                        out + 16777216L);
    qkv_gemm8<<<dim3(64, 12), 1024, 0, stream>>>(xb, Wqkv, bq, bk, bv, Qb, Kb, Vb);
    kv_reduce<<<dim3(64, KVSPLITS), 256, 0, stream>>>(Kb, Vb, KVp, Ksump);
    kv_final<<<64, 256, 0, stream>>>(KVp, Ksump, KVb, Ksum);
    attn_kernel<<<dim3(8, 64), 256, 0, stream>>>(Qb, KVb, Ksum, stdp, attn);
    out_gemm8<<<dim3(64, 4), 1024, 0, stream>>>(attn, Wob, bo, out);
}